// Round 1
// baseline (853.124 us; speedup 1.0000x reference)
//
#include <hip/hip_runtime.h>
#include <math.h>

// ---------------------------------------------------------------------------
// GCN 3-layer inference, fp32.
// Pipeline:
//   deg count -> scan -> CSR fill (by dst)           (rebuilt every call)
//   A = x @ W0            (gemm128)
//   B = relu(bn0(agg(A)+b0))                          (agg128 fused epilogue)
//   A = B @ W1            (gemm128)
//   B = relu(bn1(agg(A)+b1))
//   C = B @ W2            (gemm40)
//   out = log_softmax(agg(C)+b2)                      (agg40 fused epilogue)
// agg uses: out[n] = dinv[n]*( sum_e dinv[src]*h[src] + dinv[n]*h[n] )
// ---------------------------------------------------------------------------

__global__ __launch_bounds__(256) void k_count(const int* __restrict__ dst,
                                               int* __restrict__ deg, int E) {
    int e = blockIdx.x * 256 + threadIdx.x;
    if (e < E) atomicAdd(&deg[dst[e]], 1);
}

__global__ __launch_bounds__(1024) void k_scan1(const int* __restrict__ deg,
                                                int* __restrict__ row,
                                                int* __restrict__ bsum, int n) {
    __shared__ int wsum[16];
    int t = threadIdx.x;
    int i = blockIdx.x * 1024 + t;
    int v = (i < n) ? deg[i] : 0;
    int x = v;
#pragma unroll
    for (int d = 1; d < 64; d <<= 1) {
        int o = __shfl_up(x, d);
        if ((t & 63) >= d) x += o;
    }
    int wid = t >> 6;
    if ((t & 63) == 63) wsum[wid] = x;
    __syncthreads();
    if (t < 16) {
        int s = wsum[t];
        int y = s;
#pragma unroll
        for (int d = 1; d < 16; d <<= 1) {
            int o = __shfl_up(y, d);
            if (t >= d) y += o;
        }
        wsum[t] = y - s;  // exclusive
    }
    __syncthreads();
    int excl = x - v + wsum[wid];
    if (i < n) row[i] = excl;
    if (t == 1023) bsum[blockIdx.x] = excl + v;  // block total
}

__global__ __launch_bounds__(128) void k_scan2(const int* __restrict__ bsum,
                                               int* __restrict__ bofs, int nb) {
    __shared__ int tmp[128];
    int t = threadIdx.x;
    int v0 = (t < nb) ? bsum[t] : 0;
    tmp[t] = v0;
    __syncthreads();
    for (int d = 1; d < 128; d <<= 1) {
        int add = (t >= d) ? tmp[t - d] : 0;
        __syncthreads();
        tmp[t] += add;
        __syncthreads();
    }
    if (t < nb) bofs[t] = tmp[t] - v0;  // exclusive
}

__global__ __launch_bounds__(256) void k_final(int* __restrict__ row,
                                               const int* __restrict__ bofs,
                                               const int* __restrict__ deg,
                                               int* __restrict__ cursor,
                                               float* __restrict__ dinv, int n, int E) {
    int i = blockIdx.x * 256 + threadIdx.x;
    if (i >= n) return;
    int rs = row[i] + bofs[i >> 10];
    row[i] = rs;
    cursor[i] = rs;
    dinv[i] = rsqrtf((float)(deg[i] + 1));  // +1 self loop
    if (i == 0) row[n] = E;
}

__global__ __launch_bounds__(256) void k_fill(const int* __restrict__ src,
                                              const int* __restrict__ dst,
                                              int* __restrict__ cursor,
                                              int* __restrict__ col, int E) {
    int e = blockIdx.x * 256 + threadIdx.x;
    if (e < E) {
        int d = dst[e];
        int p = atomicAdd(&cursor[d], 1);
        col[p] = src[e];
    }
}

// C[M x 128] = A[M x 128] @ W[128 x 128], 128x128 tile / block, 8x8 per thread
__global__ __launch_bounds__(256) void k_gemm128(const float* __restrict__ A,
                                                 const float* __restrict__ W,
                                                 float* __restrict__ C, int M) {
    __shared__ float Xs[16][128];  // [k][r]
    __shared__ float Ws[16][128];  // [k][c]
    int tid = threadIdx.x;
    int tx = tid & 15, ty = tid >> 4;
    int rb = blockIdx.x * 128;
    float acc[8][8];
#pragma unroll
    for (int i = 0; i < 8; ++i)
#pragma unroll
        for (int j = 0; j < 8; ++j) acc[i][j] = 0.f;

    int sr = tid >> 1;        // 0..127 staged row
    int sk = (tid & 1) * 8;   // 0 or 8
    int gr = min(rb + sr, M - 1);
    const float* arow = &A[(size_t)gr * 128];
    int wk = tid >> 5;        // 0..7
    int wc = (tid & 31) * 4;  // 0..124

    for (int k0 = 0; k0 < 128; k0 += 16) {
        float4 xv0 = *(const float4*)&arow[k0 + sk];
        float4 xv1 = *(const float4*)&arow[k0 + sk + 4];
        float4 wv0 = *(const float4*)&W[(size_t)(k0 + wk) * 128 + wc];
        float4 wv1 = *(const float4*)&W[(size_t)(k0 + wk + 8) * 128 + wc];
        __syncthreads();
        Xs[sk + 0][sr] = xv0.x; Xs[sk + 1][sr] = xv0.y;
        Xs[sk + 2][sr] = xv0.z; Xs[sk + 3][sr] = xv0.w;
        Xs[sk + 4][sr] = xv1.x; Xs[sk + 5][sr] = xv1.y;
        Xs[sk + 6][sr] = xv1.z; Xs[sk + 7][sr] = xv1.w;
        *(float4*)&Ws[wk][wc] = wv0;
        *(float4*)&Ws[wk + 8][wc] = wv1;
        __syncthreads();
#pragma unroll
        for (int k = 0; k < 16; ++k) {
            float4 xa = *(const float4*)&Xs[k][ty * 8];
            float4 xb = *(const float4*)&Xs[k][ty * 8 + 4];
            float4 wa = *(const float4*)&Ws[k][tx * 8];
            float4 wb = *(const float4*)&Ws[k][tx * 8 + 4];
            float xr[8] = {xa.x, xa.y, xa.z, xa.w, xb.x, xb.y, xb.z, xb.w};
            float wr[8] = {wa.x, wa.y, wa.z, wa.w, wb.x, wb.y, wb.z, wb.w};
#pragma unroll
            for (int i = 0; i < 8; ++i)
#pragma unroll
                for (int j = 0; j < 8; ++j)
                    acc[i][j] = fmaf(xr[i], wr[j], acc[i][j]);
        }
    }
#pragma unroll
    for (int i = 0; i < 8; ++i) {
        int r = rb + ty * 8 + i;
        if (r < M) {
            *(float4*)&C[(size_t)r * 128 + tx * 8] =
                make_float4(acc[i][0], acc[i][1], acc[i][2], acc[i][3]);
            *(float4*)&C[(size_t)r * 128 + tx * 8 + 4] =
                make_float4(acc[i][4], acc[i][5], acc[i][6], acc[i][7]);
        }
    }
}

// C[M x 40] = A[M x 128] @ W[128 x 40]; 2 rows per thread, W staged in LDS
__global__ __launch_bounds__(256) void k_gemm40(const float* __restrict__ A,
                                                const float* __restrict__ W,
                                                float* __restrict__ C, int M) {
    __shared__ float Ws[128 * 40];
    for (int i = threadIdx.x; i < 128 * 40; i += 256) Ws[i] = W[i];
    __syncthreads();
    int r0 = blockIdx.x * 512 + threadIdx.x;
    int r1 = r0 + 256;
    float acc0[40], acc1[40];
#pragma unroll
    for (int c = 0; c < 40; ++c) { acc0[c] = 0.f; acc1[c] = 0.f; }
    const float4* x0 = (const float4*)&A[(size_t)min(r0, M - 1) * 128];
    const float4* x1 = (const float4*)&A[(size_t)min(r1, M - 1) * 128];
    for (int kb = 0; kb < 32; ++kb) {
        float4 a0 = x0[kb];
        float4 a1 = x1[kb];
        const float* wr = &Ws[kb * 160];
#pragma unroll
        for (int c4 = 0; c4 < 10; ++c4) {
            float4 wk0 = *(const float4*)&wr[c4 * 4];
            float4 wk1 = *(const float4*)&wr[40 + c4 * 4];
            float4 wk2 = *(const float4*)&wr[80 + c4 * 4];
            float4 wk3 = *(const float4*)&wr[120 + c4 * 4];
            int c = c4 * 4;
            acc0[c+0] = fmaf(a0.x,wk0.x, fmaf(a0.y,wk1.x, fmaf(a0.z,wk2.x, fmaf(a0.w,wk3.x, acc0[c+0]))));
            acc0[c+1] = fmaf(a0.x,wk0.y, fmaf(a0.y,wk1.y, fmaf(a0.z,wk2.y, fmaf(a0.w,wk3.y, acc0[c+1]))));
            acc0[c+2] = fmaf(a0.x,wk0.z, fmaf(a0.y,wk1.z, fmaf(a0.z,wk2.z, fmaf(a0.w,wk3.z, acc0[c+2]))));
            acc0[c+3] = fmaf(a0.x,wk0.w, fmaf(a0.y,wk1.w, fmaf(a0.z,wk2.w, fmaf(a0.w,wk3.w, acc0[c+3]))));
            acc1[c+0] = fmaf(a1.x,wk0.x, fmaf(a1.y,wk1.x, fmaf(a1.z,wk2.x, fmaf(a1.w,wk3.x, acc1[c+0]))));
            acc1[c+1] = fmaf(a1.x,wk0.y, fmaf(a1.y,wk1.y, fmaf(a1.z,wk2.y, fmaf(a1.w,wk3.y, acc1[c+1]))));
            acc1[c+2] = fmaf(a1.x,wk0.z, fmaf(a1.y,wk1.z, fmaf(a1.z,wk2.z, fmaf(a1.w,wk3.z, acc1[c+2]))));
            acc1[c+3] = fmaf(a1.x,wk0.w, fmaf(a1.y,wk1.w, fmaf(a1.z,wk2.w, fmaf(a1.w,wk3.w, acc1[c+3]))));
        }
    }
    if (r0 < M) {
#pragma unroll
        for (int c4 = 0; c4 < 10; ++c4)
            *(float4*)&C[(size_t)r0 * 40 + c4 * 4] =
                make_float4(acc0[c4*4], acc0[c4*4+1], acc0[c4*4+2], acc0[c4*4+3]);
    }
    if (r1 < M) {
#pragma unroll
        for (int c4 = 0; c4 < 10; ++c4)
            *(float4*)&C[(size_t)r1 * 40 + c4 * 4] =
                make_float4(acc1[c4*4], acc1[c4*4+1], acc1[c4*4+2], acc1[c4*4+3]);
    }
}

// aggregation d=128, one wave per node, lane holds features {2l, 2l+1}
__global__ __launch_bounds__(256) void k_agg128(const float* __restrict__ X,
                                                float* __restrict__ Y,
                                                const int* __restrict__ row,
                                                const int* __restrict__ col,
                                                const float* __restrict__ dinv,
                                                const float* __restrict__ bias,
                                                const float* __restrict__ g,
                                                const float* __restrict__ be,
                                                const float* __restrict__ mean,
                                                const float* __restrict__ var,
                                                int n) {
    int wid = threadIdx.x >> 6;
    int lane = threadIdx.x & 63;
    int node = blockIdx.x * 4 + wid;
    if (node >= n) return;
    const float2* xp = (const float2*)X;
    float v = dinv[node];
    float2 acc = xp[(size_t)node * 64 + lane];
    acc.x *= v;
    acc.y *= v;
    int s = row[node], e = row[node + 1];
    for (int j = s; j < e; ++j) {
        int c = col[j];
        float w = dinv[c];
        float2 xv = xp[(size_t)c * 64 + lane];
        acc.x = fmaf(w, xv.x, acc.x);
        acc.y = fmaf(w, xv.y, acc.y);
    }
    acc.x *= v;
    acc.y *= v;
    int f0 = lane * 2, f1 = f0 + 1;
    float sc0 = g[f0] * rsqrtf(var[f0] + 1e-5f);
    float sc1 = g[f1] * rsqrtf(var[f1] + 1e-5f);
    float sh0 = fmaf(sc0, bias[f0] - mean[f0], be[f0]);
    float sh1 = fmaf(sc1, bias[f1] - mean[f1], be[f1]);
    float y0 = fmaxf(fmaf(sc0, acc.x, sh0), 0.f);
    float y1 = fmaxf(fmaf(sc1, acc.y, sh1), 0.f);
    ((float2*)Y)[(size_t)node * 64 + lane] = make_float2(y0, y1);
}

// aggregation d=40 + bias + log_softmax, one wave per node (lanes 0..39 active)
__global__ __launch_bounds__(256) void k_agg40(const float* __restrict__ X,
                                               float* __restrict__ out,
                                               const int* __restrict__ row,
                                               const int* __restrict__ col,
                                               const float* __restrict__ dinv,
                                               const float* __restrict__ b2,
                                               int n) {
    int wid = threadIdx.x >> 6;
    int lane = threadIdx.x & 63;
    int node = blockIdx.x * 4 + wid;
    if (node >= n) return;
    bool active = lane < 40;
    float v = dinv[node];
    float acc = 0.f;
    if (active) acc = v * X[(size_t)node * 40 + lane];
    int s = row[node], e = row[node + 1];
    for (int j = s; j < e; ++j) {
        int c = col[j];
        float w = dinv[c];
        if (active) acc = fmaf(w, X[(size_t)c * 40 + lane], acc);
    }
    float y = active ? fmaf(v, acc, b2[lane]) : -INFINITY;
    float m = y;
#pragma unroll
    for (int d = 32; d; d >>= 1) m = fmaxf(m, __shfl_xor(m, d));
    float ex = active ? __expf(y - m) : 0.f;
    float ssum = ex;
#pragma unroll
    for (int d = 32; d; d >>= 1) ssum += __shfl_xor(ssum, d);
    if (active) out[(size_t)node * 40 + lane] = y - m - __logf(ssum);
}

extern "C" void kernel_launch(void* const* d_in, const int* in_sizes, int n_in,
                              void* d_out, int out_size, void* d_ws, size_t ws_size,
                              hipStream_t stream) {
    const float* x   = (const float*)d_in[0];
    const int*   ei  = (const int*)d_in[1];
    const float* W0  = (const float*)d_in[2];
    const float* b0  = (const float*)d_in[3];
    const float* W1  = (const float*)d_in[4];
    const float* b1  = (const float*)d_in[5];
    const float* W2  = (const float*)d_in[6];
    const float* b2  = (const float*)d_in[7];
    const float* g0  = (const float*)d_in[8];
    const float* be0 = (const float*)d_in[9];
    const float* m0  = (const float*)d_in[10];
    const float* v0  = (const float*)d_in[11];
    const float* g1  = (const float*)d_in[12];
    const float* be1 = (const float*)d_in[13];
    const float* m1  = (const float*)d_in[14];
    const float* v1  = (const float*)d_in[15];
    float* out = (float*)d_out;

    int N = in_sizes[0] / 128;
    int E = in_sizes[1] / 2;
    const int* src = ei;
    const int* dst = ei + E;

    char* ws = (char*)d_ws;
    size_t off = 0;
    auto alloc = [&](size_t bytes) -> char* {
        char* p = ws + off;
        off += (bytes + 255) & ~(size_t)255;
        return p;
    };
    float* bufA   = (float*)alloc((size_t)N * 128 * 4);
    float* bufB   = (float*)alloc((size_t)N * 128 * 4);
    float* bufC   = (float*)alloc((size_t)N * 40 * 4);
    int*   col    = (int*)alloc((size_t)E * 4);
    int*   row    = (int*)alloc((size_t)(N + 1) * 4);
    int*   cursor = (int*)alloc((size_t)N * 4);
    int*   deg    = (int*)alloc((size_t)N * 4);
    float* dinv   = (float*)alloc((size_t)N * 4);
    int*   bsum   = (int*)alloc(1024 * 4);
    int*   bofs   = (int*)alloc(1024 * 4);

    hipMemsetAsync(deg, 0, (size_t)N * 4, stream);
    int nb = (N + 1023) / 1024;
    k_count<<<(E + 255) / 256, 256, 0, stream>>>(dst, deg, E);
    k_scan1<<<nb, 1024, 0, stream>>>(deg, row, bsum, N);
    k_scan2<<<1, 128, 0, stream>>>(bsum, bofs, nb);
    k_final<<<(N + 255) / 256, 256, 0, stream>>>(row, bofs, deg, cursor, dinv, N, E);
    k_fill<<<(E + 255) / 256, 256, 0, stream>>>(src, dst, cursor, col, E);

    k_gemm128<<<(N + 127) / 128, 256, 0, stream>>>(x, W0, bufA, N);
    k_agg128<<<(N + 3) / 4, 256, 0, stream>>>(bufA, bufB, row, col, dinv, b0, g0, be0, m0, v0, N);
    k_gemm128<<<(N + 127) / 128, 256, 0, stream>>>(bufB, W1, bufA, N);
    k_agg128<<<(N + 3) / 4, 256, 0, stream>>>(bufA, bufB, row, col, dinv, b1, g1, be1, m1, v1, N);
    k_gemm40<<<(N + 511) / 512, 256, 0, stream>>>(bufB, W2, bufC, N);
    k_agg40<<<(N + 3) / 4, 256, 0, stream>>>(bufC, out, row, col, dinv, b2, N);
}

// Round 2
// 644.106 us; speedup vs baseline: 1.3245x; 1.3245x over previous
//
#include <hip/hip_runtime.h>
#include <math.h>

// ---------------------------------------------------------------------------
// GCN 3-layer inference, fp32.
//   CSR build (by dst) -> per-layer: gemm (epilogue pre-scales rows by dinv)
//   -> gather-sum aggregation (4-deep unrolled, fused BN/ReLU or log_softmax)
// agg identity: out[n] = dinv[n]*( Xs[n] + sum_e Xs[col] ),  Xs = dinv .* (A@W)
// ---------------------------------------------------------------------------

__global__ __launch_bounds__(256) void k_count(const int* __restrict__ dst,
                                               int* __restrict__ deg, int E) {
    int e = blockIdx.x * 256 + threadIdx.x;
    if (e < E) atomicAdd(&deg[dst[e]], 1);
}

__global__ __launch_bounds__(1024) void k_scan1(const int* __restrict__ deg,
                                                int* __restrict__ row,
                                                int* __restrict__ bsum, int n) {
    __shared__ int wsum[16];
    int t = threadIdx.x;
    int i = blockIdx.x * 1024 + t;
    int v = (i < n) ? deg[i] : 0;
    int x = v;
#pragma unroll
    for (int d = 1; d < 64; d <<= 1) {
        int o = __shfl_up(x, d);
        if ((t & 63) >= d) x += o;
    }
    int wid = t >> 6;
    if ((t & 63) == 63) wsum[wid] = x;
    __syncthreads();
    if (t < 16) {
        int s = wsum[t];
        int y = s;
#pragma unroll
        for (int d = 1; d < 16; d <<= 1) {
            int o = __shfl_up(y, d);
            if (t >= d) y += o;
        }
        wsum[t] = y - s;  // exclusive
    }
    __syncthreads();
    int excl = x - v + wsum[wid];
    if (i < n) row[i] = excl;
    if (t == 1023) bsum[blockIdx.x] = excl + v;  // block total
}

__global__ __launch_bounds__(128) void k_scan2(const int* __restrict__ bsum,
                                               int* __restrict__ bofs, int nb) {
    __shared__ int tmp[128];
    int t = threadIdx.x;
    int v0 = (t < nb) ? bsum[t] : 0;
    tmp[t] = v0;
    __syncthreads();
    for (int d = 1; d < 128; d <<= 1) {
        int add = (t >= d) ? tmp[t - d] : 0;
        __syncthreads();
        tmp[t] += add;
        __syncthreads();
    }
    if (t < nb) bofs[t] = tmp[t] - v0;  // exclusive
}

__global__ __launch_bounds__(256) void k_final(int* __restrict__ row,
                                               const int* __restrict__ bofs,
                                               const int* __restrict__ deg,
                                               int* __restrict__ cursor,
                                               float* __restrict__ dinv, int n, int E) {
    int i = blockIdx.x * 256 + threadIdx.x;
    if (i >= n) return;
    int rs = row[i] + bofs[i >> 10];
    row[i] = rs;
    cursor[i] = rs;
    dinv[i] = rsqrtf((float)(deg[i] + 1));  // +1 self loop
    if (i == 0) row[n] = E;
}

__global__ __launch_bounds__(256) void k_fill(const int* __restrict__ src,
                                              const int* __restrict__ dst,
                                              int* __restrict__ cursor,
                                              int* __restrict__ col, int E) {
    int e = blockIdx.x * 256 + threadIdx.x;
    if (e < E) {
        int d = dst[e];
        int p = atomicAdd(&cursor[d], 1);
        col[p] = src[e];
    }
}

// C[r] = dinv[r] * (A[r] @ W), A: Mx128, W: 128x128. 128x128 tile, 8x8/thread.
__global__ __launch_bounds__(256) void k_gemm128(const float* __restrict__ A,
                                                 const float* __restrict__ W,
                                                 float* __restrict__ C,
                                                 const float* __restrict__ dinv,
                                                 int M) {
    __shared__ float Xs[16][128];  // [k][r]
    __shared__ float Ws[16][128];  // [k][c]
    int tid = threadIdx.x;
    int tx = tid & 15, ty = tid >> 4;
    int rb = blockIdx.x * 128;
    float acc[8][8];
#pragma unroll
    for (int i = 0; i < 8; ++i)
#pragma unroll
        for (int j = 0; j < 8; ++j) acc[i][j] = 0.f;

    int sr = tid >> 1;        // 0..127 staged row
    int sk = (tid & 1) * 8;   // 0 or 8
    int gr = min(rb + sr, M - 1);
    const float* arow = &A[(size_t)gr * 128];
    int wk = tid >> 5;        // 0..7
    int wc = (tid & 31) * 4;  // 0..124

    for (int k0 = 0; k0 < 128; k0 += 16) {
        float4 xv0 = *(const float4*)&arow[k0 + sk];
        float4 xv1 = *(const float4*)&arow[k0 + sk + 4];
        float4 wv0 = *(const float4*)&W[(size_t)(k0 + wk) * 128 + wc];
        float4 wv1 = *(const float4*)&W[(size_t)(k0 + wk + 8) * 128 + wc];
        __syncthreads();
        Xs[sk + 0][sr] = xv0.x; Xs[sk + 1][sr] = xv0.y;
        Xs[sk + 2][sr] = xv0.z; Xs[sk + 3][sr] = xv0.w;
        Xs[sk + 4][sr] = xv1.x; Xs[sk + 5][sr] = xv1.y;
        Xs[sk + 6][sr] = xv1.z; Xs[sk + 7][sr] = xv1.w;
        *(float4*)&Ws[wk][wc] = wv0;
        *(float4*)&Ws[wk + 8][wc] = wv1;
        __syncthreads();
#pragma unroll
        for (int k = 0; k < 16; ++k) {
            float4 xa = *(const float4*)&Xs[k][ty * 8];
            float4 xb = *(const float4*)&Xs[k][ty * 8 + 4];
            float4 wa = *(const float4*)&Ws[k][tx * 8];
            float4 wb = *(const float4*)&Ws[k][tx * 8 + 4];
            float xr[8] = {xa.x, xa.y, xa.z, xa.w, xb.x, xb.y, xb.z, xb.w};
            float wr[8] = {wa.x, wa.y, wa.z, wa.w, wb.x, wb.y, wb.z, wb.w};
#pragma unroll
            for (int i = 0; i < 8; ++i)
#pragma unroll
                for (int j = 0; j < 8; ++j)
                    acc[i][j] = fmaf(xr[i], wr[j], acc[i][j]);
        }
    }
#pragma unroll
    for (int i = 0; i < 8; ++i) {
        int r = rb + ty * 8 + i;
        if (r < M) {
            float s = dinv[r];
            *(float4*)&C[(size_t)r * 128 + tx * 8] =
                make_float4(s * acc[i][0], s * acc[i][1], s * acc[i][2], s * acc[i][3]);
            *(float4*)&C[(size_t)r * 128 + tx * 8 + 4] =
                make_float4(s * acc[i][4], s * acc[i][5], s * acc[i][6], s * acc[i][7]);
        }
    }
}

// C[r] = dinv[r] * (A[r] @ W), A: Mx128, W: 128x40. 2 rows/thread.
__global__ __launch_bounds__(256) void k_gemm40(const float* __restrict__ A,
                                                const float* __restrict__ W,
                                                float* __restrict__ C,
                                                const float* __restrict__ dinv,
                                                int M) {
    __shared__ float Ws[128 * 40];
    for (int i = threadIdx.x; i < 128 * 40; i += 256) Ws[i] = W[i];
    __syncthreads();
    int r0 = blockIdx.x * 512 + threadIdx.x;
    int r1 = r0 + 256;
    float acc0[40], acc1[40];
#pragma unroll
    for (int c = 0; c < 40; ++c) { acc0[c] = 0.f; acc1[c] = 0.f; }
    const float4* x0 = (const float4*)&A[(size_t)min(r0, M - 1) * 128];
    const float4* x1 = (const float4*)&A[(size_t)min(r1, M - 1) * 128];
    for (int kb = 0; kb < 32; ++kb) {
        float4 a0 = x0[kb];
        float4 a1 = x1[kb];
        const float* wr = &Ws[kb * 160];
#pragma unroll
        for (int c4 = 0; c4 < 10; ++c4) {
            float4 wk0 = *(const float4*)&wr[c4 * 4];
            float4 wk1 = *(const float4*)&wr[40 + c4 * 4];
            float4 wk2 = *(const float4*)&wr[80 + c4 * 4];
            float4 wk3 = *(const float4*)&wr[120 + c4 * 4];
            int c = c4 * 4;
            acc0[c+0] = fmaf(a0.x,wk0.x, fmaf(a0.y,wk1.x, fmaf(a0.z,wk2.x, fmaf(a0.w,wk3.x, acc0[c+0]))));
            acc0[c+1] = fmaf(a0.x,wk0.y, fmaf(a0.y,wk1.y, fmaf(a0.z,wk2.y, fmaf(a0.w,wk3.y, acc0[c+1]))));
            acc0[c+2] = fmaf(a0.x,wk0.z, fmaf(a0.y,wk1.z, fmaf(a0.z,wk2.z, fmaf(a0.w,wk3.z, acc0[c+2]))));
            acc0[c+3] = fmaf(a0.x,wk0.w, fmaf(a0.y,wk1.w, fmaf(a0.z,wk2.w, fmaf(a0.w,wk3.w, acc0[c+3]))));
            acc1[c+0] = fmaf(a1.x,wk0.x, fmaf(a1.y,wk1.x, fmaf(a1.z,wk2.x, fmaf(a1.w,wk3.x, acc1[c+0]))));
            acc1[c+1] = fmaf(a1.x,wk0.y, fmaf(a1.y,wk1.y, fmaf(a1.z,wk2.y, fmaf(a1.w,wk3.y, acc1[c+1]))));
            acc1[c+2] = fmaf(a1.x,wk0.z, fmaf(a1.y,wk1.z, fmaf(a1.z,wk2.z, fmaf(a1.w,wk3.z, acc1[c+2]))));
            acc1[c+3] = fmaf(a1.x,wk0.w, fmaf(a1.y,wk1.w, fmaf(a1.z,wk2.w, fmaf(a1.w,wk3.w, acc1[c+3]))));
        }
    }
    if (r0 < M) {
        float s = dinv[r0];
#pragma unroll
        for (int c4 = 0; c4 < 10; ++c4)
            *(float4*)&C[(size_t)r0 * 40 + c4 * 4] =
                make_float4(s*acc0[c4*4], s*acc0[c4*4+1], s*acc0[c4*4+2], s*acc0[c4*4+3]);
    }
    if (r1 < M) {
        float s = dinv[r1];
#pragma unroll
        for (int c4 = 0; c4 < 10; ++c4)
            *(float4*)&C[(size_t)r1 * 40 + c4 * 4] =
                make_float4(s*acc1[c4*4], s*acc1[c4*4+1], s*acc1[c4*4+2], s*acc1[c4*4+3]);
    }
}

// aggregation d=128 over pre-scaled Xs; 4-deep unrolled gather; fused BN+ReLU.
__global__ __launch_bounds__(256) void k_agg128(const float* __restrict__ X,
                                                float* __restrict__ Y,
                                                const int* __restrict__ row,
                                                const int* __restrict__ col,
                                                const float* __restrict__ dinv,
                                                const float* __restrict__ bias,
                                                const float* __restrict__ g,
                                                const float* __restrict__ be,
                                                const float* __restrict__ mean,
                                                const float* __restrict__ var,
                                                int n) {
    int wid = threadIdx.x >> 6;
    int lane = threadIdx.x & 63;
    int node = blockIdx.x * 4 + wid;
    if (node >= n) return;
    const float2* xp = (const float2*)X;
    int s = row[node], e = row[node + 1];
    float2 a0 = xp[(size_t)node * 64 + lane];  // self (pre-scaled)
    float2 a1 = make_float2(0.f, 0.f);
    float2 a2 = make_float2(0.f, 0.f);
    float2 a3 = make_float2(0.f, 0.f);
    int j = s;
    for (; j + 4 <= e; j += 4) {
        int c0 = col[j], c1 = col[j + 1], c2 = col[j + 2], c3 = col[j + 3];
        float2 x0 = xp[(size_t)c0 * 64 + lane];
        float2 x1 = xp[(size_t)c1 * 64 + lane];
        float2 x2 = xp[(size_t)c2 * 64 + lane];
        float2 x3 = xp[(size_t)c3 * 64 + lane];
        a0.x += x0.x; a0.y += x0.y;
        a1.x += x1.x; a1.y += x1.y;
        a2.x += x2.x; a2.y += x2.y;
        a3.x += x3.x; a3.y += x3.y;
    }
    for (; j < e; ++j) {
        int c = col[j];
        float2 xv = xp[(size_t)c * 64 + lane];
        a0.x += xv.x; a0.y += xv.y;
    }
    float v = dinv[node];
    float ax = v * ((a0.x + a1.x) + (a2.x + a3.x));
    float ay = v * ((a0.y + a1.y) + (a2.y + a3.y));
    int f0 = lane * 2, f1 = f0 + 1;
    float sc0 = g[f0] * rsqrtf(var[f0] + 1e-5f);
    float sc1 = g[f1] * rsqrtf(var[f1] + 1e-5f);
    float sh0 = fmaf(sc0, bias[f0] - mean[f0], be[f0]);
    float sh1 = fmaf(sc1, bias[f1] - mean[f1], be[f1]);
    float y0 = fmaxf(fmaf(sc0, ax, sh0), 0.f);
    float y1 = fmaxf(fmaf(sc1, ay, sh1), 0.f);
    ((float2*)Y)[(size_t)node * 64 + lane] = make_float2(y0, y1);
}

// aggregation d=40 over pre-scaled Xs + bias + log_softmax.
__global__ __launch_bounds__(256) void k_agg40(const float* __restrict__ X,
                                               float* __restrict__ out,
                                               const int* __restrict__ row,
                                               const int* __restrict__ col,
                                               const float* __restrict__ dinv,
                                               const float* __restrict__ b2,
                                               int n) {
    int wid = threadIdx.x >> 6;
    int lane = threadIdx.x & 63;
    int node = blockIdx.x * 4 + wid;
    if (node >= n) return;
    bool active = lane < 40;
    int s = row[node], e = row[node + 1];
    float a0 = 0.f, a1 = 0.f, a2 = 0.f, a3 = 0.f;
    if (active) a0 = X[(size_t)node * 40 + lane];  // self (pre-scaled)
    int j = s;
    for (; j + 4 <= e; j += 4) {
        int c0 = col[j], c1 = col[j + 1], c2 = col[j + 2], c3 = col[j + 3];
        if (active) {
            a0 += X[(size_t)c0 * 40 + lane];
            a1 += X[(size_t)c1 * 40 + lane];
            a2 += X[(size_t)c2 * 40 + lane];
            a3 += X[(size_t)c3 * 40 + lane];
        }
    }
    for (; j < e; ++j) {
        int c = col[j];
        if (active) a0 += X[(size_t)c * 40 + lane];
    }
    float v = dinv[node];
    float y = active ? fmaf(v, (a0 + a1) + (a2 + a3), b2[lane]) : -INFINITY;
    float m = y;
#pragma unroll
    for (int d = 32; d; d >>= 1) m = fmaxf(m, __shfl_xor(m, d));
    float ex = active ? __expf(y - m) : 0.f;
    float ssum = ex;
#pragma unroll
    for (int d = 32; d; d >>= 1) ssum += __shfl_xor(ssum, d);
    if (active) out[(size_t)node * 40 + lane] = y - m - __logf(ssum);
}

extern "C" void kernel_launch(void* const* d_in, const int* in_sizes, int n_in,
                              void* d_out, int out_size, void* d_ws, size_t ws_size,
                              hipStream_t stream) {
    const float* x   = (const float*)d_in[0];
    const int*   ei  = (const int*)d_in[1];
    const float* W0  = (const float*)d_in[2];
    const float* b0  = (const float*)d_in[3];
    const float* W1  = (const float*)d_in[4];
    const float* b1  = (const float*)d_in[5];
    const float* W2  = (const float*)d_in[6];
    const float* b2  = (const float*)d_in[7];
    const float* g0  = (const float*)d_in[8];
    const float* be0 = (const float*)d_in[9];
    const float* m0  = (const float*)d_in[10];
    const float* v0  = (const float*)d_in[11];
    const float* g1  = (const float*)d_in[12];
    const float* be1 = (const float*)d_in[13];
    const float* m1  = (const float*)d_in[14];
    const float* v1  = (const float*)d_in[15];
    float* out = (float*)d_out;

    int N = in_sizes[0] / 128;
    int E = in_sizes[1] / 2;
    const int* src = ei;
    const int* dst = ei + E;

    char* ws = (char*)d_ws;
    size_t off = 0;
    auto alloc = [&](size_t bytes) -> char* {
        char* p = ws + off;
        off += (bytes + 255) & ~(size_t)255;
        return p;
    };
    float* bufA   = (float*)alloc((size_t)N * 128 * 4);
    float* bufB   = (float*)alloc((size_t)N * 128 * 4);
    float* bufC   = (float*)alloc((size_t)N * 40 * 4);
    int*   col    = (int*)alloc((size_t)E * 4);
    int*   row    = (int*)alloc((size_t)(N + 1) * 4);
    int*   cursor = (int*)alloc((size_t)N * 4);
    int*   deg    = (int*)alloc((size_t)N * 4);
    float* dinv   = (float*)alloc((size_t)N * 4);
    int*   bsum   = (int*)alloc(1024 * 4);
    int*   bofs   = (int*)alloc(1024 * 4);

    hipMemsetAsync(deg, 0, (size_t)N * 4, stream);
    int nb = (N + 1023) / 1024;
    k_count<<<(E + 255) / 256, 256, 0, stream>>>(dst, deg, E);
    k_scan1<<<nb, 1024, 0, stream>>>(deg, row, bsum, N);
    k_scan2<<<1, 128, 0, stream>>>(bsum, bofs, nb);
    k_final<<<(N + 255) / 256, 256, 0, stream>>>(row, bofs, deg, cursor, dinv, N, E);
    k_fill<<<(E + 255) / 256, 256, 0, stream>>>(src, dst, cursor, col, E);

    k_gemm128<<<(N + 127) / 128, 256, 0, stream>>>(x, W0, bufA, dinv, N);
    k_agg128<<<(N + 3) / 4, 256, 0, stream>>>(bufA, bufB, row, col, dinv, b0, g0, be0, m0, v0, N);
    k_gemm128<<<(N + 127) / 128, 256, 0, stream>>>(bufB, W1, bufA, dinv, N);
    k_agg128<<<(N + 3) / 4, 256, 0, stream>>>(bufA, bufB, row, col, dinv, b1, g1, be1, m1, v1, N);
    k_gemm40<<<(N + 511) / 512, 256, 0, stream>>>(bufB, W2, bufC, dinv, N);
    k_agg40<<<(N + 3) / 4, 256, 0, stream>>>(bufC, out, row, col, dinv, b2, N);
}

// Round 3
// 632.241 us; speedup vs baseline: 1.3494x; 1.0188x over previous
//
#include <hip/hip_runtime.h>
#include <math.h>

// ---------------------------------------------------------------------------
// GCN 3-layer inference, fp32.
// CSR build (bucketed two-phase, write-locality-aware):
//   k_hist: cell histogram, cell = (dst>>7)*8 + (blockIdx&7)   [group ~ XCD]
//   k_scan_cells: exclusive scan of 6256 cells (offsets in bkt AND col)
//   k_scatter: (src,dst) -> bkt[cell appends]   (dense, same-XCD lines)
//   k_bucket: per-bucket block: LDS deg+scan -> row/dinv, LDS-cursor col fill
// Layers: gemm (epilogue pre-scales rows by dinv) -> gather-sum agg
// agg identity: out[n] = dinv[n]*( Xs[n] + sum_e Xs[col] ),  Xs = dinv.*(A@W)
// ---------------------------------------------------------------------------

#define BSHIFT 7
#define BSIZE 128  // nodes per bucket

__global__ __launch_bounds__(256) void k_hist(const int* __restrict__ dst,
                                              int* __restrict__ cellcnt, int E) {
    int e = blockIdx.x * 256 + threadIdx.x;
    int g = blockIdx.x & 7;
    if (e < E) atomicAdd(&cellcnt[((dst[e] >> BSHIFT) << 3) + g], 1);
}

// exclusive scan of cellcnt[0..NC) -> cellcur (single block, 256 threads)
__global__ __launch_bounds__(256) void k_scan_cells(const int* __restrict__ cellcnt,
                                                    int* __restrict__ cellcur, int NC) {
    __shared__ int wsum[4];
    int t = threadIdx.x;
    int per = (NC + 255) / 256;
    int lo = t * per, hi = min(lo + per, NC);
    int sum = 0;
    for (int i = lo; i < hi; ++i) sum += cellcnt[i];
    int x = sum;
#pragma unroll
    for (int d = 1; d < 64; d <<= 1) {
        int o = __shfl_up(x, d);
        if ((t & 63) >= d) x += o;
    }
    int wid = t >> 6;
    if ((t & 63) == 63) wsum[wid] = x;
    __syncthreads();
    if (t < 4) {
        int s = wsum[t];
        int y = s;
#pragma unroll
        for (int d = 1; d < 4; d <<= 1) {
            int o = __shfl_up(y, d);
            if (t >= d) y += o;
        }
        wsum[t] = y - s;  // exclusive over waves
    }
    __syncthreads();
    int run = (x - sum) + wsum[wid];
    for (int i = lo; i < hi; ++i) {
        cellcur[i] = run;
        run += cellcnt[i];
    }
}

__global__ __launch_bounds__(256) void k_scatter(const int* __restrict__ src,
                                                 const int* __restrict__ dst,
                                                 int* __restrict__ cellcur,
                                                 int2* __restrict__ bkt, int E) {
    int e = blockIdx.x * 256 + threadIdx.x;
    int g = blockIdx.x & 7;
    if (e < E) {
        int d = dst[e];
        int p = atomicAdd(&cellcur[((d >> BSHIFT) << 3) + g], 1);
        bkt[p] = make_int2(src[e], d);
    }
}

// After k_scatter, cellcur[c] == end offset of cell c. Bucket b range:
// [ b?cellcur[8b-1]:0 , cellcur[8b+7] ). Same offsets index col.
__global__ __launch_bounds__(256) void k_bucket(const int2* __restrict__ bkt,
                                                const int* __restrict__ cellcur,
                                                int* __restrict__ col,
                                                int* __restrict__ row,
                                                float* __restrict__ dinv,
                                                int N, int E) {
    __shared__ int degl[BSIZE];
    __shared__ int curl[BSIZE];
    int b = blockIdx.x;
    int t = threadIdx.x;
    int start = (b == 0) ? 0 : cellcur[(b << 3) - 1];
    int end = cellcur[(b << 3) + 7];
    int nbase = b << BSHIFT;
    if (t < BSIZE) degl[t] = 0;
    __syncthreads();
    for (int i = start + t; i < end; i += 256) {
        int2 sd = bkt[i];
        atomicAdd(&degl[sd.y & (BSIZE - 1)], 1);
    }
    __syncthreads();
    if (t < 64) {
        int d0 = degl[2 * t], d1 = degl[2 * t + 1];
        int s = d0 + d1;
        int x = s;
#pragma unroll
        for (int dd = 1; dd < 64; dd <<= 1) {
            int o = __shfl_up(x, dd);
            if (t >= dd) x += o;
        }
        int excl = x - s;  // exclusive within bucket
        curl[2 * t] = excl;
        curl[2 * t + 1] = excl + d0;
        int n0 = nbase + 2 * t, n1 = n0 + 1;
        if (n0 < N) { row[n0] = start + excl;      dinv[n0] = rsqrtf((float)(d0 + 1)); }
        if (n1 < N) { row[n1] = start + excl + d0; dinv[n1] = rsqrtf((float)(d1 + 1)); }
    }
    __syncthreads();
    for (int i = start + t; i < end; i += 256) {
        int2 sd = bkt[i];
        int p = start + atomicAdd(&curl[sd.y & (BSIZE - 1)], 1);
        col[p] = sd.x;
    }
    if (b == 0 && t == 0) row[N] = E;
}

// C[r] = dinv[r] * (A[r] @ W), A: Mx128, W: 128x128. 128x128 tile, 8x8/thread.
__global__ __launch_bounds__(256) void k_gemm128(const float* __restrict__ A,
                                                 const float* __restrict__ W,
                                                 float* __restrict__ C,
                                                 const float* __restrict__ dinv,
                                                 int M) {
    __shared__ float Xs[16][128];  // [k][r]
    __shared__ float Ws[16][128];  // [k][c]
    int tid = threadIdx.x;
    int tx = tid & 15, ty = tid >> 4;
    int rb = blockIdx.x * 128;
    float acc[8][8];
#pragma unroll
    for (int i = 0; i < 8; ++i)
#pragma unroll
        for (int j = 0; j < 8; ++j) acc[i][j] = 0.f;

    int sr = tid >> 1;        // 0..127 staged row
    int sk = (tid & 1) * 8;   // 0 or 8
    int gr = min(rb + sr, M - 1);
    const float* arow = &A[(size_t)gr * 128];
    int wk = tid >> 5;        // 0..7
    int wc = (tid & 31) * 4;  // 0..124

    for (int k0 = 0; k0 < 128; k0 += 16) {
        float4 xv0 = *(const float4*)&arow[k0 + sk];
        float4 xv1 = *(const float4*)&arow[k0 + sk + 4];
        float4 wv0 = *(const float4*)&W[(size_t)(k0 + wk) * 128 + wc];
        float4 wv1 = *(const float4*)&W[(size_t)(k0 + wk + 8) * 128 + wc];
        __syncthreads();
        Xs[sk + 0][sr] = xv0.x; Xs[sk + 1][sr] = xv0.y;
        Xs[sk + 2][sr] = xv0.z; Xs[sk + 3][sr] = xv0.w;
        Xs[sk + 4][sr] = xv1.x; Xs[sk + 5][sr] = xv1.y;
        Xs[sk + 6][sr] = xv1.z; Xs[sk + 7][sr] = xv1.w;
        *(float4*)&Ws[wk][wc] = wv0;
        *(float4*)&Ws[wk + 8][wc] = wv1;
        __syncthreads();
#pragma unroll
        for (int k = 0; k < 16; ++k) {
            float4 xa = *(const float4*)&Xs[k][ty * 8];
            float4 xb = *(const float4*)&Xs[k][ty * 8 + 4];
            float4 wa = *(const float4*)&Ws[k][tx * 8];
            float4 wb = *(const float4*)&Ws[k][tx * 8 + 4];
            float xr[8] = {xa.x, xa.y, xa.z, xa.w, xb.x, xb.y, xb.z, xb.w};
            float wr[8] = {wa.x, wa.y, wa.z, wa.w, wb.x, wb.y, wb.z, wb.w};
#pragma unroll
            for (int i = 0; i < 8; ++i)
#pragma unroll
                for (int j = 0; j < 8; ++j)
                    acc[i][j] = fmaf(xr[i], wr[j], acc[i][j]);
        }
    }
#pragma unroll
    for (int i = 0; i < 8; ++i) {
        int r = rb + ty * 8 + i;
        if (r < M) {
            float s = dinv[r];
            *(float4*)&C[(size_t)r * 128 + tx * 8] =
                make_float4(s * acc[i][0], s * acc[i][1], s * acc[i][2], s * acc[i][3]);
            *(float4*)&C[(size_t)r * 128 + tx * 8 + 4] =
                make_float4(s * acc[i][4], s * acc[i][5], s * acc[i][6], s * acc[i][7]);
        }
    }
}

// C[r] = dinv[r] * (A[r] @ W), A: Mx128, W: 128x40. 2 rows/thread.
__global__ __launch_bounds__(256) void k_gemm40(const float* __restrict__ A,
                                                const float* __restrict__ W,
                                                float* __restrict__ C,
                                                const float* __restrict__ dinv,
                                                int M) {
    __shared__ float Ws[128 * 40];
    for (int i = threadIdx.x; i < 128 * 40; i += 256) Ws[i] = W[i];
    __syncthreads();
    int r0 = blockIdx.x * 512 + threadIdx.x;
    int r1 = r0 + 256;
    float acc0[40], acc1[40];
#pragma unroll
    for (int c = 0; c < 40; ++c) { acc0[c] = 0.f; acc1[c] = 0.f; }
    const float4* x0 = (const float4*)&A[(size_t)min(r0, M - 1) * 128];
    const float4* x1 = (const float4*)&A[(size_t)min(r1, M - 1) * 128];
    for (int kb = 0; kb < 32; ++kb) {
        float4 a0 = x0[kb];
        float4 a1 = x1[kb];
        const float* wr = &Ws[kb * 160];
#pragma unroll
        for (int c4 = 0; c4 < 10; ++c4) {
            float4 wk0 = *(const float4*)&wr[c4 * 4];
            float4 wk1 = *(const float4*)&wr[40 + c4 * 4];
            float4 wk2 = *(const float4*)&wr[80 + c4 * 4];
            float4 wk3 = *(const float4*)&wr[120 + c4 * 4];
            int c = c4 * 4;
            acc0[c+0] = fmaf(a0.x,wk0.x, fmaf(a0.y,wk1.x, fmaf(a0.z,wk2.x, fmaf(a0.w,wk3.x, acc0[c+0]))));
            acc0[c+1] = fmaf(a0.x,wk0.y, fmaf(a0.y,wk1.y, fmaf(a0.z,wk2.y, fmaf(a0.w,wk3.y, acc0[c+1]))));
            acc0[c+2] = fmaf(a0.x,wk0.z, fmaf(a0.y,wk1.z, fmaf(a0.z,wk2.z, fmaf(a0.w,wk3.z, acc0[c+2]))));
            acc0[c+3] = fmaf(a0.x,wk0.w, fmaf(a0.y,wk1.w, fmaf(a0.z,wk2.w, fmaf(a0.w,wk3.w, acc0[c+3]))));
            acc1[c+0] = fmaf(a1.x,wk0.x, fmaf(a1.y,wk1.x, fmaf(a1.z,wk2.x, fmaf(a1.w,wk3.x, acc1[c+0]))));
            acc1[c+1] = fmaf(a1.x,wk0.y, fmaf(a1.y,wk1.y, fmaf(a1.z,wk2.y, fmaf(a1.w,wk3.y, acc1[c+1]))));
            acc1[c+2] = fmaf(a1.x,wk0.z, fmaf(a1.y,wk1.z, fmaf(a1.z,wk2.z, fmaf(a1.w,wk3.z, acc1[c+2]))));
            acc1[c+3] = fmaf(a1.x,wk0.w, fmaf(a1.y,wk1.w, fmaf(a1.z,wk2.w, fmaf(a1.w,wk3.w, acc1[c+3]))));
        }
    }
    if (r0 < M) {
        float s = dinv[r0];
#pragma unroll
        for (int c4 = 0; c4 < 10; ++c4)
            *(float4*)&C[(size_t)r0 * 40 + c4 * 4] =
                make_float4(s*acc0[c4*4], s*acc0[c4*4+1], s*acc0[c4*4+2], s*acc0[c4*4+3]);
    }
    if (r1 < M) {
        float s = dinv[r1];
#pragma unroll
        for (int c4 = 0; c4 < 10; ++c4)
            *(float4*)&C[(size_t)r1 * 40 + c4 * 4] =
                make_float4(s*acc1[c4*4], s*acc1[c4*4+1], s*acc1[c4*4+2], s*acc1[c4*4+3]);
    }
}

// aggregation d=128 over pre-scaled Xs; 4-deep unrolled gather; fused BN+ReLU.
__global__ __launch_bounds__(256) void k_agg128(const float* __restrict__ X,
                                                float* __restrict__ Y,
                                                const int* __restrict__ row,
                                                const int* __restrict__ col,
                                                const float* __restrict__ dinv,
                                                const float* __restrict__ bias,
                                                const float* __restrict__ g,
                                                const float* __restrict__ be,
                                                const float* __restrict__ mean,
                                                const float* __restrict__ var,
                                                int n) {
    int wid = threadIdx.x >> 6;
    int lane = threadIdx.x & 63;
    int node = blockIdx.x * 4 + wid;
    if (node >= n) return;
    const float2* xp = (const float2*)X;
    int s = row[node], e = row[node + 1];
    float2 a0 = xp[(size_t)node * 64 + lane];  // self (pre-scaled)
    float2 a1 = make_float2(0.f, 0.f);
    float2 a2 = make_float2(0.f, 0.f);
    float2 a3 = make_float2(0.f, 0.f);
    int j = s;
    for (; j + 4 <= e; j += 4) {
        int c0 = col[j], c1 = col[j + 1], c2 = col[j + 2], c3 = col[j + 3];
        float2 x0 = xp[(size_t)c0 * 64 + lane];
        float2 x1 = xp[(size_t)c1 * 64 + lane];
        float2 x2 = xp[(size_t)c2 * 64 + lane];
        float2 x3 = xp[(size_t)c3 * 64 + lane];
        a0.x += x0.x; a0.y += x0.y;
        a1.x += x1.x; a1.y += x1.y;
        a2.x += x2.x; a2.y += x2.y;
        a3.x += x3.x; a3.y += x3.y;
    }
    for (; j < e; ++j) {
        int c = col[j];
        float2 xv = xp[(size_t)c * 64 + lane];
        a0.x += xv.x; a0.y += xv.y;
    }
    float v = dinv[node];
    float ax = v * ((a0.x + a1.x) + (a2.x + a3.x));
    float ay = v * ((a0.y + a1.y) + (a2.y + a3.y));
    int f0 = lane * 2, f1 = f0 + 1;
    float sc0 = g[f0] * rsqrtf(var[f0] + 1e-5f);
    float sc1 = g[f1] * rsqrtf(var[f1] + 1e-5f);
    float sh0 = fmaf(sc0, bias[f0] - mean[f0], be[f0]);
    float sh1 = fmaf(sc1, bias[f1] - mean[f1], be[f1]);
    float y0 = fmaxf(fmaf(sc0, ax, sh0), 0.f);
    float y1 = fmaxf(fmaf(sc1, ay, sh1), 0.f);
    ((float2*)Y)[(size_t)node * 64 + lane] = make_float2(y0, y1);
}

// aggregation d=40 over pre-scaled Xs + bias + log_softmax.
__global__ __launch_bounds__(256) void k_agg40(const float* __restrict__ X,
                                               float* __restrict__ out,
                                               const int* __restrict__ row,
                                               const int* __restrict__ col,
                                               const float* __restrict__ dinv,
                                               const float* __restrict__ b2,
                                               int n) {
    int wid = threadIdx.x >> 6;
    int lane = threadIdx.x & 63;
    int node = blockIdx.x * 4 + wid;
    if (node >= n) return;
    bool active = lane < 40;
    int s = row[node], e = row[node + 1];
    float a0 = 0.f, a1 = 0.f, a2 = 0.f, a3 = 0.f;
    if (active) a0 = X[(size_t)node * 40 + lane];  // self (pre-scaled)
    int j = s;
    for (; j + 4 <= e; j += 4) {
        int c0 = col[j], c1 = col[j + 1], c2 = col[j + 2], c3 = col[j + 3];
        if (active) {
            a0 += X[(size_t)c0 * 40 + lane];
            a1 += X[(size_t)c1 * 40 + lane];
            a2 += X[(size_t)c2 * 40 + lane];
            a3 += X[(size_t)c3 * 40 + lane];
        }
    }
    for (; j < e; ++j) {
        int c = col[j];
        if (active) a0 += X[(size_t)c * 40 + lane];
    }
    float v = dinv[node];
    float y = active ? fmaf(v, (a0 + a1) + (a2 + a3), b2[lane]) : -INFINITY;
    float m = y;
#pragma unroll
    for (int d = 32; d; d >>= 1) m = fmaxf(m, __shfl_xor(m, d));
    float ex = active ? __expf(y - m) : 0.f;
    float ssum = ex;
#pragma unroll
    for (int d = 32; d; d >>= 1) ssum += __shfl_xor(ssum, d);
    if (active) out[(size_t)node * 40 + lane] = y - m - __logf(ssum);
}

extern "C" void kernel_launch(void* const* d_in, const int* in_sizes, int n_in,
                              void* d_out, int out_size, void* d_ws, size_t ws_size,
                              hipStream_t stream) {
    const float* x   = (const float*)d_in[0];
    const int*   ei  = (const int*)d_in[1];
    const float* W0  = (const float*)d_in[2];
    const float* b0  = (const float*)d_in[3];
    const float* W1  = (const float*)d_in[4];
    const float* b1  = (const float*)d_in[5];
    const float* W2  = (const float*)d_in[6];
    const float* b2  = (const float*)d_in[7];
    const float* g0  = (const float*)d_in[8];
    const float* be0 = (const float*)d_in[9];
    const float* m0  = (const float*)d_in[10];
    const float* v0  = (const float*)d_in[11];
    const float* g1  = (const float*)d_in[12];
    const float* be1 = (const float*)d_in[13];
    const float* m1  = (const float*)d_in[14];
    const float* v1  = (const float*)d_in[15];
    float* out = (float*)d_out;

    int N = in_sizes[0] / 128;
    int E = in_sizes[1] / 2;
    const int* src = ei;
    const int* dst = ei + E;

    int NBUCKET = (N + BSIZE - 1) / BSIZE;
    int NCELL = NBUCKET * 8;

    char* ws = (char*)d_ws;
    size_t off = 0;
    auto alloc = [&](size_t bytes) -> char* {
        char* p = ws + off;
        off += (bytes + 255) & ~(size_t)255;
        return p;
    };
    float* bufA    = (float*)alloc((size_t)N * 128 * 4);
    float* bufB    = (float*)alloc((size_t)N * 128 * 4);
    float* bufC    = (float*)alloc((size_t)N * 40 * 4);
    int*   col     = (int*)alloc((size_t)E * 4);
    int*   row     = (int*)alloc((size_t)(N + 1) * 4);
    float* dinv    = (float*)alloc((size_t)N * 4);
    int*   cellcnt = (int*)alloc((size_t)NCELL * 4);
    int*   cellcur = (int*)alloc((size_t)NCELL * 4);
    int2*  bkt     = (int2*)bufA;  // alias: bkt dead before gemm0 writes bufA

    hipMemsetAsync(cellcnt, 0, (size_t)NCELL * 4, stream);
    int egrid = (E + 255) / 256;
    k_hist<<<egrid, 256, 0, stream>>>(dst, cellcnt, E);
    k_scan_cells<<<1, 256, 0, stream>>>(cellcnt, cellcur, NCELL);
    k_scatter<<<egrid, 256, 0, stream>>>(src, dst, cellcur, bkt, E);
    k_bucket<<<NBUCKET, 256, 0, stream>>>(bkt, cellcur, col, row, dinv, N, E);

    k_gemm128<<<(N + 127) / 128, 256, 0, stream>>>(x, W0, bufA, dinv, N);
    k_agg128<<<(N + 3) / 4, 256, 0, stream>>>(bufA, bufB, row, col, dinv, b0, g0, be0, m0, v0, N);
    k_gemm128<<<(N + 127) / 128, 256, 0, stream>>>(bufB, W1, bufA, dinv, N);
    k_agg128<<<(N + 3) / 4, 256, 0, stream>>>(bufA, bufB, row, col, dinv, b1, g1, be1, m1, v1, N);
    k_gemm40<<<(N + 511) / 512, 256, 0, stream>>>(bufB, W2, bufC, dinv, N);
    k_agg40<<<(N + 3) / 4, 256, 0, stream>>>(bufC, out, row, col, dinv, b2, N);
}

// Round 4
// 589.287 us; speedup vs baseline: 1.4477x; 1.0729x over previous
//
#include <hip/hip_runtime.h>
#include <math.h>

// ---------------------------------------------------------------------------
// GCN 3-layer inference. fp32 math, bf16 intermediate feature buffers
// (halves the gather traffic in aggregation, the dominant cost).
// CSR build (bucketed two-phase, write-locality-aware):
//   k_hist / k_scan_cells / k_scatter / k_bucket
// Layers: gemm (epilogue scales rows by dinv, packs bf16) -> gather-sum agg
// agg identity: out[n] = dinv[n]*( Xs[n] + sum_e Xs[col] ),  Xs = dinv.*(A@W)
// ---------------------------------------------------------------------------

#define BSHIFT 7
#define BSIZE 128  // nodes per bucket

typedef unsigned short u16;
typedef unsigned int u32;

__device__ inline float bflo(u32 u) { return __uint_as_float(u << 16); }
__device__ inline float bfhi(u32 u) { return __uint_as_float(u & 0xffff0000u); }
__device__ inline u16 f2bf(float f) {  // RNE
    u32 b = __float_as_uint(f);
    b += 0x7fff + ((b >> 16) & 1);
    return (u16)(b >> 16);
}
__device__ inline u32 pack2(float lo, float hi) {
    return (u32)f2bf(lo) | ((u32)f2bf(hi) << 16);
}

// ------------------------------- CSR build ---------------------------------

__global__ __launch_bounds__(256) void k_hist(const int* __restrict__ dst,
                                              int* __restrict__ cellcnt, int E) {
    int e = blockIdx.x * 256 + threadIdx.x;
    int g = blockIdx.x & 7;
    if (e < E) atomicAdd(&cellcnt[((dst[e] >> BSHIFT) << 3) + g], 1);
}

__global__ __launch_bounds__(256) void k_scan_cells(const int* __restrict__ cellcnt,
                                                    int* __restrict__ cellcur, int NC) {
    __shared__ int wsum[4];
    int t = threadIdx.x;
    int per = (NC + 255) / 256;
    int lo = t * per, hi = min(lo + per, NC);
    int sum = 0;
    for (int i = lo; i < hi; ++i) sum += cellcnt[i];
    int x = sum;
#pragma unroll
    for (int d = 1; d < 64; d <<= 1) {
        int o = __shfl_up(x, d);
        if ((t & 63) >= d) x += o;
    }
    int wid = t >> 6;
    if ((t & 63) == 63) wsum[wid] = x;
    __syncthreads();
    if (t < 4) {
        int s = wsum[t];
        int y = s;
#pragma unroll
        for (int d = 1; d < 4; d <<= 1) {
            int o = __shfl_up(y, d);
            if (t >= d) y += o;
        }
        wsum[t] = y - s;
    }
    __syncthreads();
    int run = (x - sum) + wsum[wid];
    for (int i = lo; i < hi; ++i) {
        cellcur[i] = run;
        run += cellcnt[i];
    }
}

__global__ __launch_bounds__(256) void k_scatter(const int* __restrict__ src,
                                                 const int* __restrict__ dst,
                                                 int* __restrict__ cellcur,
                                                 int2* __restrict__ bkt, int E) {
    int e = blockIdx.x * 256 + threadIdx.x;
    int g = blockIdx.x & 7;
    if (e < E) {
        int d = dst[e];
        int p = atomicAdd(&cellcur[((d >> BSHIFT) << 3) + g], 1);
        bkt[p] = make_int2(src[e], d);
    }
}

__global__ __launch_bounds__(256) void k_bucket(const int2* __restrict__ bkt,
                                                const int* __restrict__ cellcur,
                                                int* __restrict__ col,
                                                int* __restrict__ row,
                                                float* __restrict__ dinv,
                                                int N, int E) {
    __shared__ int degl[BSIZE];
    __shared__ int curl[BSIZE];
    int b = blockIdx.x;
    int t = threadIdx.x;
    int start = (b == 0) ? 0 : cellcur[(b << 3) - 1];
    int end = cellcur[(b << 3) + 7];
    int nbase = b << BSHIFT;
    if (t < BSIZE) degl[t] = 0;
    __syncthreads();
    for (int i = start + t; i < end; i += 256) {
        int2 sd = bkt[i];
        atomicAdd(&degl[sd.y & (BSIZE - 1)], 1);
    }
    __syncthreads();
    if (t < 64) {
        int d0 = degl[2 * t], d1 = degl[2 * t + 1];
        int s = d0 + d1;
        int x = s;
#pragma unroll
        for (int dd = 1; dd < 64; dd <<= 1) {
            int o = __shfl_up(x, dd);
            if (t >= dd) x += o;
        }
        int excl = x - s;
        curl[2 * t] = excl;
        curl[2 * t + 1] = excl + d0;
        int n0 = nbase + 2 * t, n1 = n0 + 1;
        if (n0 < N) { row[n0] = start + excl;      dinv[n0] = rsqrtf((float)(d0 + 1)); }
        if (n1 < N) { row[n1] = start + excl + d0; dinv[n1] = rsqrtf((float)(d1 + 1)); }
    }
    __syncthreads();
    for (int i = start + t; i < end; i += 256) {
        int2 sd = bkt[i];
        int p = start + atomicAdd(&curl[sd.y & (BSIZE - 1)], 1);
        col[p] = sd.x;
    }
    if (b == 0 && t == 0) row[N] = E;
}

// --------------------------------- GEMMs -----------------------------------

// C[r](bf16) = dinv[r] * (A[r] @ W). A: Mx128 (fp32 or bf16), W: 128x128 fp32.
template <bool BF16A>
__global__ __launch_bounds__(256) void k_gemm128(const void* __restrict__ Av,
                                                 const float* __restrict__ W,
                                                 u16* __restrict__ C,
                                                 const float* __restrict__ dinv,
                                                 int M) {
    __shared__ float Xs[16][128];  // [k][r]
    __shared__ float Ws[16][128];  // [k][c]
    int tid = threadIdx.x;
    int tx = tid & 15, ty = tid >> 4;
    int rb = blockIdx.x * 128;
    float acc[8][8];
#pragma unroll
    for (int i = 0; i < 8; ++i)
#pragma unroll
        for (int j = 0; j < 8; ++j) acc[i][j] = 0.f;

    int sr = tid >> 1;        // staged row 0..127
    int sk = (tid & 1) * 8;   // k sub-offset 0 or 8
    int gr = min(rb + sr, M - 1);
    int wk = tid >> 5;        // 0..7
    int wc = (tid & 31) * 4;  // 0..124

    for (int k0 = 0; k0 < 128; k0 += 16) {
        float xr8[8];
        if (BF16A) {
            const uint4* arow = (const uint4*)((const u16*)Av + (size_t)gr * 128);
            uint4 u = arow[(k0 + sk) >> 3];
            xr8[0] = bflo(u.x); xr8[1] = bfhi(u.x);
            xr8[2] = bflo(u.y); xr8[3] = bfhi(u.y);
            xr8[4] = bflo(u.z); xr8[5] = bfhi(u.z);
            xr8[6] = bflo(u.w); xr8[7] = bfhi(u.w);
        } else {
            const float* arow = (const float*)Av + (size_t)gr * 128;
            float4 xv0 = *(const float4*)&arow[k0 + sk];
            float4 xv1 = *(const float4*)&arow[k0 + sk + 4];
            xr8[0] = xv0.x; xr8[1] = xv0.y; xr8[2] = xv0.z; xr8[3] = xv0.w;
            xr8[4] = xv1.x; xr8[5] = xv1.y; xr8[6] = xv1.z; xr8[7] = xv1.w;
        }
        float4 wv0 = *(const float4*)&W[(size_t)(k0 + wk) * 128 + wc];
        float4 wv1 = *(const float4*)&W[(size_t)(k0 + wk + 8) * 128 + wc];
        __syncthreads();
#pragma unroll
        for (int i = 0; i < 8; ++i) Xs[sk + i][sr] = xr8[i];
        *(float4*)&Ws[wk][wc] = wv0;
        *(float4*)&Ws[wk + 8][wc] = wv1;
        __syncthreads();
#pragma unroll
        for (int k = 0; k < 16; ++k) {
            float4 xa = *(const float4*)&Xs[k][ty * 8];
            float4 xb = *(const float4*)&Xs[k][ty * 8 + 4];
            float4 wa = *(const float4*)&Ws[k][tx * 8];
            float4 wb = *(const float4*)&Ws[k][tx * 8 + 4];
            float xr[8] = {xa.x, xa.y, xa.z, xa.w, xb.x, xb.y, xb.z, xb.w};
            float wr[8] = {wa.x, wa.y, wa.z, wa.w, wb.x, wb.y, wb.z, wb.w};
#pragma unroll
            for (int i = 0; i < 8; ++i)
#pragma unroll
                for (int j = 0; j < 8; ++j)
                    acc[i][j] = fmaf(xr[i], wr[j], acc[i][j]);
        }
    }
#pragma unroll
    for (int i = 0; i < 8; ++i) {
        int r = rb + ty * 8 + i;
        if (r < M) {
            float s = dinv[r];
            uint4 o;
            o.x = pack2(s * acc[i][0], s * acc[i][1]);
            o.y = pack2(s * acc[i][2], s * acc[i][3]);
            o.z = pack2(s * acc[i][4], s * acc[i][5]);
            o.w = pack2(s * acc[i][6], s * acc[i][7]);
            *(uint4*)&C[(size_t)r * 128 + tx * 8] = o;
        }
    }
}

// C[r](fp32) = dinv[r] * (A[r] @ W), A: Mx128 bf16, W: 128x40 fp32.
__global__ __launch_bounds__(256) void k_gemm40(const u16* __restrict__ A,
                                                const float* __restrict__ W,
                                                float* __restrict__ C,
                                                const float* __restrict__ dinv,
                                                int M) {
    __shared__ float Ws[128 * 40];
    for (int i = threadIdx.x; i < 128 * 40; i += 256) Ws[i] = W[i];
    __syncthreads();
    int r0 = blockIdx.x * 512 + threadIdx.x;
    int r1 = r0 + 256;
    float acc0[40], acc1[40];
#pragma unroll
    for (int c = 0; c < 40; ++c) { acc0[c] = 0.f; acc1[c] = 0.f; }
    const uint2* x0 = (const uint2*)(A + (size_t)min(r0, M - 1) * 128);
    const uint2* x1 = (const uint2*)(A + (size_t)min(r1, M - 1) * 128);
    for (int kb = 0; kb < 32; ++kb) {
        uint2 ua = x0[kb];
        uint2 ub = x1[kb];
        float a0x = bflo(ua.x), a0y = bfhi(ua.x), a0z = bflo(ua.y), a0w = bfhi(ua.y);
        float a1x = bflo(ub.x), a1y = bfhi(ub.x), a1z = bflo(ub.y), a1w = bfhi(ub.y);
        const float* wr = &Ws[kb * 160];
#pragma unroll
        for (int c4 = 0; c4 < 10; ++c4) {
            float4 wk0 = *(const float4*)&wr[c4 * 4];
            float4 wk1 = *(const float4*)&wr[40 + c4 * 4];
            float4 wk2 = *(const float4*)&wr[80 + c4 * 4];
            float4 wk3 = *(const float4*)&wr[120 + c4 * 4];
            int c = c4 * 4;
            acc0[c+0] = fmaf(a0x,wk0.x, fmaf(a0y,wk1.x, fmaf(a0z,wk2.x, fmaf(a0w,wk3.x, acc0[c+0]))));
            acc0[c+1] = fmaf(a0x,wk0.y, fmaf(a0y,wk1.y, fmaf(a0z,wk2.y, fmaf(a0w,wk3.y, acc0[c+1]))));
            acc0[c+2] = fmaf(a0x,wk0.z, fmaf(a0y,wk1.z, fmaf(a0z,wk2.z, fmaf(a0w,wk3.z, acc0[c+2]))));
            acc0[c+3] = fmaf(a0x,wk0.w, fmaf(a0y,wk1.w, fmaf(a0z,wk2.w, fmaf(a0w,wk3.w, acc0[c+3]))));
            acc1[c+0] = fmaf(a1x,wk0.x, fmaf(a1y,wk1.x, fmaf(a1z,wk2.x, fmaf(a1w,wk3.x, acc1[c+0]))));
            acc1[c+1] = fmaf(a1x,wk0.y, fmaf(a1y,wk1.y, fmaf(a1z,wk2.y, fmaf(a1w,wk3.y, acc1[c+1]))));
            acc1[c+2] = fmaf(a1x,wk0.z, fmaf(a1y,wk1.z, fmaf(a1z,wk2.z, fmaf(a1w,wk3.z, acc1[c+2]))));
            acc1[c+3] = fmaf(a1x,wk0.w, fmaf(a1y,wk1.w, fmaf(a1z,wk2.w, fmaf(a1w,wk3.w, acc1[c+3]))));
        }
    }
    if (r0 < M) {
        float s = dinv[r0];
#pragma unroll
        for (int c4 = 0; c4 < 10; ++c4)
            *(float4*)&C[(size_t)r0 * 40 + c4 * 4] =
                make_float4(s*acc0[c4*4], s*acc0[c4*4+1], s*acc0[c4*4+2], s*acc0[c4*4+3]);
    }
    if (r1 < M) {
        float s = dinv[r1];
#pragma unroll
        for (int c4 = 0; c4 < 10; ++c4)
            *(float4*)&C[(size_t)r1 * 40 + c4 * 4] =
                make_float4(s*acc1[c4*4], s*acc1[c4*4+1], s*acc1[c4*4+2], s*acc1[c4*4+3]);
    }
}

// ------------------------------ aggregation --------------------------------

// d=128 bf16 gather-sum; 2 nodes per wave (32 lanes x 4 feats each);
// 8/2/1 unrolled edge loop; fused bias+BN+ReLU; bf16 in/out.
__global__ __launch_bounds__(256) void k_agg128(const u16* __restrict__ X,
                                                u16* __restrict__ Y,
                                                const int* __restrict__ row,
                                                const int* __restrict__ col,
                                                const float* __restrict__ dinv,
                                                const float* __restrict__ bias,
                                                const float* __restrict__ g,
                                                const float* __restrict__ be,
                                                const float* __restrict__ mean,
                                                const float* __restrict__ var,
                                                int n) {
    int tid = threadIdx.x;
    int wid = tid >> 6, lane = tid & 63;
    int half = lane >> 5, l5 = lane & 31;
    int node = (blockIdx.x * 4 + wid) * 2 + half;
    bool valid = node < n;
    int nc = valid ? node : (n - 1);
    const uint2* xp = (const uint2*)X;  // 32 x uint2 per row (4 bf16 each)
    int s = row[nc], e = row[nc + 1];
    uint2 v = xp[(size_t)nc * 32 + l5];  // self (pre-scaled)
    float a0 = bflo(v.x), a1 = bfhi(v.x), a2 = bflo(v.y), a3 = bfhi(v.y);
    float b0 = 0, b1 = 0, b2 = 0, b3 = 0;
    float c0 = 0, c1 = 0, c2 = 0, c3 = 0;
    float d0 = 0, d1 = 0, d2 = 0, d3 = 0;
    int j = s;
    for (; j + 8 <= e; j += 8) {
        int e0 = col[j], e1 = col[j+1], e2 = col[j+2], e3 = col[j+3];
        int e4 = col[j+4], e5 = col[j+5], e6 = col[j+6], e7 = col[j+7];
        uint2 x0 = xp[(size_t)e0 * 32 + l5];
        uint2 x1 = xp[(size_t)e1 * 32 + l5];
        uint2 x2 = xp[(size_t)e2 * 32 + l5];
        uint2 x3 = xp[(size_t)e3 * 32 + l5];
        uint2 x4 = xp[(size_t)e4 * 32 + l5];
        uint2 x5 = xp[(size_t)e5 * 32 + l5];
        uint2 x6 = xp[(size_t)e6 * 32 + l5];
        uint2 x7 = xp[(size_t)e7 * 32 + l5];
        a0 += bflo(x0.x); a1 += bfhi(x0.x); a2 += bflo(x0.y); a3 += bfhi(x0.y);
        b0 += bflo(x1.x); b1 += bfhi(x1.x); b2 += bflo(x1.y); b3 += bfhi(x1.y);
        c0 += bflo(x2.x); c1 += bfhi(x2.x); c2 += bflo(x2.y); c3 += bfhi(x2.y);
        d0 += bflo(x3.x); d1 += bfhi(x3.x); d2 += bflo(x3.y); d3 += bfhi(x3.y);
        a0 += bflo(x4.x); a1 += bfhi(x4.x); a2 += bflo(x4.y); a3 += bfhi(x4.y);
        b0 += bflo(x5.x); b1 += bfhi(x5.x); b2 += bflo(x5.y); b3 += bfhi(x5.y);
        c0 += bflo(x6.x); c1 += bfhi(x6.x); c2 += bflo(x6.y); c3 += bfhi(x6.y);
        d0 += bflo(x7.x); d1 += bfhi(x7.x); d2 += bflo(x7.y); d3 += bfhi(x7.y);
    }
    for (; j + 2 <= e; j += 2) {
        int e0 = col[j], e1 = col[j+1];
        uint2 x0 = xp[(size_t)e0 * 32 + l5];
        uint2 x1 = xp[(size_t)e1 * 32 + l5];
        a0 += bflo(x0.x); a1 += bfhi(x0.x); a2 += bflo(x0.y); a3 += bfhi(x0.y);
        b0 += bflo(x1.x); b1 += bfhi(x1.x); b2 += bflo(x1.y); b3 += bfhi(x1.y);
    }
    if (j < e) {
        uint2 x0 = xp[(size_t)col[j] * 32 + l5];
        c0 += bflo(x0.x); c1 += bfhi(x0.x); c2 += bflo(x0.y); c3 += bfhi(x0.y);
    }
    float dv = dinv[nc];
    float s0 = dv * ((a0 + b0) + (c0 + d0));
    float s1 = dv * ((a1 + b1) + (c1 + d1));
    float s2 = dv * ((a2 + b2) + (c2 + d2));
    float s3 = dv * ((a3 + b3) + (c3 + d3));
    float4 g4 = ((const float4*)g)[l5];
    float4 be4 = ((const float4*)be)[l5];
    float4 m4 = ((const float4*)mean)[l5];
    float4 v4 = ((const float4*)var)[l5];
    float4 bi4 = ((const float4*)bias)[l5];
    float sc0 = g4.x * rsqrtf(v4.x + 1e-5f);
    float sc1 = g4.y * rsqrtf(v4.y + 1e-5f);
    float sc2 = g4.z * rsqrtf(v4.z + 1e-5f);
    float sc3 = g4.w * rsqrtf(v4.w + 1e-5f);
    float y0 = fmaxf(fmaf(sc0, s0, fmaf(sc0, bi4.x - m4.x, be4.x)), 0.f);
    float y1 = fmaxf(fmaf(sc1, s1, fmaf(sc1, bi4.y - m4.y, be4.y)), 0.f);
    float y2 = fmaxf(fmaf(sc2, s2, fmaf(sc2, bi4.z - m4.z, be4.z)), 0.f);
    float y3 = fmaxf(fmaf(sc3, s3, fmaf(sc3, bi4.w - m4.w, be4.w)), 0.f);
    if (valid) {
        uint2 o;
        o.x = pack2(y0, y1);
        o.y = pack2(y2, y3);
        ((uint2*)Y)[(size_t)node * 32 + l5] = o;
    }
}

// d=40 fp32 gather-sum + bias + log_softmax (lanes 0..39 active).
__global__ __launch_bounds__(256) void k_agg40(const float* __restrict__ X,
                                               float* __restrict__ out,
                                               const int* __restrict__ row,
                                               const int* __restrict__ col,
                                               const float* __restrict__ dinv,
                                               const float* __restrict__ b2,
                                               int n) {
    int wid = threadIdx.x >> 6;
    int lane = threadIdx.x & 63;
    int node = blockIdx.x * 4 + wid;
    if (node >= n) return;
    bool active = lane < 40;
    int s = row[node], e = row[node + 1];
    float a0 = 0.f, a1 = 0.f, a2 = 0.f, a3 = 0.f;
    float a4 = 0.f, a5 = 0.f, a6 = 0.f, a7 = 0.f;
    if (active) a0 = X[(size_t)node * 40 + lane];  // self (pre-scaled)
    int j = s;
    for (; j + 8 <= e; j += 8) {
        int c0 = col[j], c1 = col[j+1], c2 = col[j+2], c3 = col[j+3];
        int c4 = col[j+4], c5 = col[j+5], c6 = col[j+6], c7 = col[j+7];
        if (active) {
            a0 += X[(size_t)c0 * 40 + lane];
            a1 += X[(size_t)c1 * 40 + lane];
            a2 += X[(size_t)c2 * 40 + lane];
            a3 += X[(size_t)c3 * 40 + lane];
            a4 += X[(size_t)c4 * 40 + lane];
            a5 += X[(size_t)c5 * 40 + lane];
            a6 += X[(size_t)c6 * 40 + lane];
            a7 += X[(size_t)c7 * 40 + lane];
        }
    }
    for (; j + 2 <= e; j += 2) {
        int c0 = col[j], c1 = col[j+1];
        if (active) {
            a0 += X[(size_t)c0 * 40 + lane];
            a1 += X[(size_t)c1 * 40 + lane];
        }
    }
    if (j < e && active) a2 += X[(size_t)col[j] * 40 + lane];
    float v = dinv[node];
    float tot = ((a0 + a1) + (a2 + a3)) + ((a4 + a5) + (a6 + a7));
    float y = active ? fmaf(v, tot, b2[lane]) : -INFINITY;
    float m = y;
#pragma unroll
    for (int d = 32; d; d >>= 1) m = fmaxf(m, __shfl_xor(m, d));
    float ex = active ? __expf(y - m) : 0.f;
    float ssum = ex;
#pragma unroll
    for (int d = 32; d; d >>= 1) ssum += __shfl_xor(ssum, d);
    if (active) out[(size_t)node * 40 + lane] = y - m - __logf(ssum);
}

// --------------------------------- launch ----------------------------------

extern "C" void kernel_launch(void* const* d_in, const int* in_sizes, int n_in,
                              void* d_out, int out_size, void* d_ws, size_t ws_size,
                              hipStream_t stream) {
    const float* x   = (const float*)d_in[0];
    const int*   ei  = (const int*)d_in[1];
    const float* W0  = (const float*)d_in[2];
    const float* b0  = (const float*)d_in[3];
    const float* W1  = (const float*)d_in[4];
    const float* b1  = (const float*)d_in[5];
    const float* W2  = (const float*)d_in[6];
    const float* b2  = (const float*)d_in[7];
    const float* g0  = (const float*)d_in[8];
    const float* be0 = (const float*)d_in[9];
    const float* m0  = (const float*)d_in[10];
    const float* v0  = (const float*)d_in[11];
    const float* g1  = (const float*)d_in[12];
    const float* be1 = (const float*)d_in[13];
    const float* m1  = (const float*)d_in[14];
    const float* v1  = (const float*)d_in[15];
    float* out = (float*)d_out;

    int N = in_sizes[0] / 128;
    int E = in_sizes[1] / 2;
    const int* src = ei;
    const int* dst = ei + E;

    int NBUCKET = (N + BSIZE - 1) / BSIZE;
    int NCELL = NBUCKET * 8;

    char* ws = (char*)d_ws;
    size_t off = 0;
    auto alloc = [&](size_t bytes) -> char* {
        char* p = ws + off;
        off += (bytes + 255) & ~(size_t)255;
        return p;
    };
    u16*   XsA     = (u16*)alloc((size_t)N * 128 * 2);   // gemm out / agg in
    u16*   hB      = (u16*)alloc((size_t)N * 128 * 2);   // agg out / gemm in
    float* bufC    = (float*)alloc((size_t)N * 40 * 4);
    int*   col     = (int*)alloc((size_t)E * 4);
    int*   row     = (int*)alloc((size_t)(N + 1) * 4);
    float* dinv    = (float*)alloc((size_t)N * 4);
    int*   cellcnt = (int*)alloc((size_t)NCELL * 4);
    int*   cellcur = (int*)alloc((size_t)NCELL * 4);
    int2*  bkt     = (int2*)XsA;  // alias: bkt dead before gemm0 writes XsA

    hipMemsetAsync(cellcnt, 0, (size_t)NCELL * 4, stream);
    int egrid = (E + 255) / 256;
    k_hist<<<egrid, 256, 0, stream>>>(dst, cellcnt, E);
    k_scan_cells<<<1, 256, 0, stream>>>(cellcnt, cellcur, NCELL);
    k_scatter<<<egrid, 256, 0, stream>>>(src, dst, cellcur, bkt, E);
    k_bucket<<<NBUCKET, 256, 0, stream>>>(bkt, cellcur, col, row, dinv, N, E);

    k_gemm128<false><<<(N + 127) / 128, 256, 0, stream>>>(x, W0, XsA, dinv, N);
    k_agg128<<<(N + 7) / 8, 256, 0, stream>>>(XsA, hB, row, col, dinv, b0, g0, be0, m0, v0, N);
    k_gemm128<true><<<(N + 127) / 128, 256, 0, stream>>>(hB, W1, XsA, dinv, N);
    k_agg128<<<(N + 7) / 8, 256, 0, stream>>>(XsA, hB, row, col, dinv, b1, g1, be1, m1, v1, N);
    k_gemm40<<<(N + 511) / 512, 256, 0, stream>>>(hB, W2, bufC, dinv, N);
    k_agg40<<<(N + 3) / 4, 256, 0, stream>>>(bufC, out, row, col, dinv, b2, N);
}

// Round 5
// 397.543 us; speedup vs baseline: 2.1460x; 1.4823x over previous
//
#include <hip/hip_runtime.h>
#include <math.h>

// ---------------------------------------------------------------------------
// GCN 3-layer inference. fp32 math, bf16 intermediate feature buffers.
// CSR build via LDS-multisplit radix partition (dense global writes):
//   k_hist1: coarse hist, 196 bins (dst>>9, 512 nodes/bin)
//   k_scan1: 1-block scan -> base1/cur1
//   k_part1: 8192-edge blocks: LDS hist+scan+group, 1 atomic/bin, dense copy-out
//            bkt[] entries packed u32 = src<<9 | (dst & 511)
//   k_csr:   per-bucket block: LDS node-degrees -> row/dinv, LDS-cursor col fill
// Layers: gemm (epilogue scales rows by dinv, packs bf16) -> gather-sum agg
// agg identity: out[n] = dinv[n]*( Xs[n] + sum_e Xs[col] ),  Xs = dinv.*(A@W)
// ---------------------------------------------------------------------------

#define CSHIFT 9
#define CSZ 512         // nodes per coarse bucket
#define PCHUNK 8192     // edges per k_part1 block

typedef unsigned short u16;
typedef unsigned int u32;
typedef unsigned char u8;

__device__ inline float bflo(u32 u) { return __uint_as_float(u << 16); }
__device__ inline float bfhi(u32 u) { return __uint_as_float(u & 0xffff0000u); }
__device__ inline u16 f2bf(float f) {  // RNE
    u32 b = __float_as_uint(f);
    b += 0x7fff + ((b >> 16) & 1);
    return (u16)(b >> 16);
}
__device__ inline u32 pack2(float lo, float hi) {
    return (u32)f2bf(lo) | ((u32)f2bf(hi) << 16);
}

// ------------------------------- CSR build ---------------------------------

// coarse histogram: LDS-staged, few global atomics
__global__ __launch_bounds__(256) void k_hist1(const int* __restrict__ dst,
                                               int* __restrict__ hist1,
                                               int E, int NB) {
    __shared__ int h[256];
    int t = threadIdx.x;
    h[t] = 0;
    __syncthreads();
    for (int i = blockIdx.x * 256 * 16 + t; i < min(E, (blockIdx.x + 1) * 256 * 16);
         i += 256)
        atomicAdd(&h[dst[i] >> CSHIFT], 1);
    __syncthreads();
    if (t < NB && h[t]) atomicAdd(&hist1[t], h[t]);
}

// exclusive scan of hist1[0..NB) -> base1 (+sentinel), copy to cur1
__global__ __launch_bounds__(256) void k_scan1(const int* __restrict__ hist1,
                                               int* __restrict__ base1,
                                               int* __restrict__ cur1,
                                               int NB, int E) {
    __shared__ int sc[256];
    int t = threadIdx.x;
    int v = (t < NB) ? hist1[t] : 0;
    sc[t] = v;
    __syncthreads();
    for (int d = 1; d < 256; d <<= 1) {
        int add = (t >= d) ? sc[t - d] : 0;
        __syncthreads();
        sc[t] += add;
        __syncthreads();
    }
    if (t < NB) {
        int excl = sc[t] - v;
        base1[t] = excl;
        cur1[t] = excl;
    }
    if (t == 0) base1[NB] = E;
}

// multisplit partition: group PCHUNK edges by coarse bin in LDS, dense copy-out
__global__ __launch_bounds__(256) void k_part1(const int* __restrict__ src,
                                               const int* __restrict__ dst,
                                               int* __restrict__ cur1,
                                               u32* __restrict__ bkt,
                                               int E, int NB) {
    __shared__ u32 stage[PCHUNK];
    __shared__ u8 sbin[PCHUNK];
    __shared__ int cnt[256];   // per-bin count
    __shared__ int lbase[256]; // per-bin LDS exclusive base
    __shared__ int lcur[256];  // per-bin LDS cursor
    __shared__ int gb[256];    // per-bin global base
    int t = threadIdx.x;
    int base = blockIdx.x * PCHUNK;
    int n = min(PCHUNK, E - base);
    cnt[t] = 0;
    __syncthreads();
    for (int i = t; i < n; i += 256) atomicAdd(&cnt[dst[base + i] >> CSHIFT], 1);
    __syncthreads();
    int v = cnt[t];
    lbase[t] = v;
    __syncthreads();
    for (int d = 1; d < 256; d <<= 1) {
        int add = (t >= d) ? lbase[t - d] : 0;
        __syncthreads();
        lbase[t] += add;
        __syncthreads();
    }
    {
        int excl = lbase[t] - v;
        __syncthreads();
        lbase[t] = excl;
        lcur[t] = excl;
        if (t < NB && v) gb[t] = atomicAdd(&cur1[t], v);
    }
    __syncthreads();
    for (int i = t; i < n; i += 256) {
        int d = dst[base + i];
        int s = src[base + i];
        int bin = d >> CSHIFT;
        int p = atomicAdd(&lcur[bin], 1);
        stage[p] = ((u32)s << CSHIFT) | (u32)(d & (CSZ - 1));
        sbin[p] = (u8)bin;
    }
    __syncthreads();
    for (int k = t; k < n; k += 256) {
        int bin = sbin[k];
        bkt[gb[bin] + (k - lbase[bin])] = stage[k];
    }
}

// per coarse bucket: node degrees -> row/dinv, then col fill (L2-resident region)
__global__ __launch_bounds__(256) void k_csr(const u32* __restrict__ bkt,
                                             const int* __restrict__ base1,
                                             int* __restrict__ col,
                                             int* __restrict__ row,
                                             float* __restrict__ dinv,
                                             int N, int E) {
    __shared__ int deg[CSZ];
    __shared__ int cur[CSZ];
    __shared__ int sc[256];
    int b = blockIdx.x;
    int t = threadIdx.x;
    int start = base1[b];
    int end = base1[b + 1];
    int nbase = b << CSHIFT;
    deg[t] = 0;
    deg[t + 256] = 0;
    __syncthreads();
    for (int i = start + t; i < end; i += 256)
        atomicAdd(&deg[bkt[i] & (CSZ - 1)], 1);
    __syncthreads();
    int d0 = deg[2 * t], d1 = deg[2 * t + 1];
    int s = d0 + d1;
    sc[t] = s;
    __syncthreads();
    for (int d = 1; d < 256; d <<= 1) {
        int add = (t >= d) ? sc[t - d] : 0;
        __syncthreads();
        sc[t] += add;
        __syncthreads();
    }
    int excl = sc[t] - s;
    cur[2 * t] = excl;
    cur[2 * t + 1] = excl + d0;
    int n0 = nbase + 2 * t, n1 = n0 + 1;
    if (n0 < N) { row[n0] = start + excl;      dinv[n0] = rsqrtf((float)(d0 + 1)); }
    if (n1 < N) { row[n1] = start + excl + d0; dinv[n1] = rsqrtf((float)(d1 + 1)); }
    __syncthreads();
    for (int i = start + t; i < end; i += 256) {
        u32 v = bkt[i];
        int p = start + atomicAdd(&cur[v & (CSZ - 1)], 1);
        col[p] = (int)(v >> CSHIFT);
    }
    if (b == 0 && t == 0) row[N] = E;
}

// --------------------------------- GEMMs -----------------------------------

// C[r](bf16) = dinv[r] * (A[r] @ W). A: Mx128 (fp32 or bf16), W: 128x128 fp32.
template <bool BF16A>
__global__ __launch_bounds__(256) void k_gemm128(const void* __restrict__ Av,
                                                 const float* __restrict__ W,
                                                 u16* __restrict__ C,
                                                 const float* __restrict__ dinv,
                                                 int M) {
    __shared__ float Xs[16][128];  // [k][r]
    __shared__ float Ws[16][128];  // [k][c]
    int tid = threadIdx.x;
    int tx = tid & 15, ty = tid >> 4;
    int rb = blockIdx.x * 128;
    float acc[8][8];
#pragma unroll
    for (int i = 0; i < 8; ++i)
#pragma unroll
        for (int j = 0; j < 8; ++j) acc[i][j] = 0.f;

    int sr = tid >> 1;        // staged row 0..127
    int sk = (tid & 1) * 8;   // k sub-offset 0 or 8
    int gr = min(rb + sr, M - 1);
    int wk = tid >> 5;        // 0..7
    int wc = (tid & 31) * 4;  // 0..124

    for (int k0 = 0; k0 < 128; k0 += 16) {
        float xr8[8];
        if (BF16A) {
            const uint4* arow = (const uint4*)((const u16*)Av + (size_t)gr * 128);
            uint4 u = arow[(k0 + sk) >> 3];
            xr8[0] = bflo(u.x); xr8[1] = bfhi(u.x);
            xr8[2] = bflo(u.y); xr8[3] = bfhi(u.y);
            xr8[4] = bflo(u.z); xr8[5] = bfhi(u.z);
            xr8[6] = bflo(u.w); xr8[7] = bfhi(u.w);
        } else {
            const float* arow = (const float*)Av + (size_t)gr * 128;
            float4 xv0 = *(const float4*)&arow[k0 + sk];
            float4 xv1 = *(const float4*)&arow[k0 + sk + 4];
            xr8[0] = xv0.x; xr8[1] = xv0.y; xr8[2] = xv0.z; xr8[3] = xv0.w;
            xr8[4] = xv1.x; xr8[5] = xv1.y; xr8[6] = xv1.z; xr8[7] = xv1.w;
        }
        float4 wv0 = *(const float4*)&W[(size_t)(k0 + wk) * 128 + wc];
        float4 wv1 = *(const float4*)&W[(size_t)(k0 + wk + 8) * 128 + wc];
        __syncthreads();
#pragma unroll
        for (int i = 0; i < 8; ++i) Xs[sk + i][sr] = xr8[i];
        *(float4*)&Ws[wk][wc] = wv0;
        *(float4*)&Ws[wk + 8][wc] = wv1;
        __syncthreads();
#pragma unroll
        for (int k = 0; k < 16; ++k) {
            float4 xa = *(const float4*)&Xs[k][ty * 8];
            float4 xb = *(const float4*)&Xs[k][ty * 8 + 4];
            float4 wa = *(const float4*)&Ws[k][tx * 8];
            float4 wb = *(const float4*)&Ws[k][tx * 8 + 4];
            float xr[8] = {xa.x, xa.y, xa.z, xa.w, xb.x, xb.y, xb.z, xb.w};
            float wr[8] = {wa.x, wa.y, wa.z, wa.w, wb.x, wb.y, wb.z, wb.w};
#pragma unroll
            for (int i = 0; i < 8; ++i)
#pragma unroll
                for (int j = 0; j < 8; ++j)
                    acc[i][j] = fmaf(xr[i], wr[j], acc[i][j]);
        }
    }
#pragma unroll
    for (int i = 0; i < 8; ++i) {
        int r = rb + ty * 8 + i;
        if (r < M) {
            float s = dinv[r];
            uint4 o;
            o.x = pack2(s * acc[i][0], s * acc[i][1]);
            o.y = pack2(s * acc[i][2], s * acc[i][3]);
            o.z = pack2(s * acc[i][4], s * acc[i][5]);
            o.w = pack2(s * acc[i][6], s * acc[i][7]);
            *(uint4*)&C[(size_t)r * 128 + tx * 8] = o;
        }
    }
}

// C[r](fp32) = dinv[r] * (A[r] @ W), A: Mx128 bf16, W: 128x40 fp32.
__global__ __launch_bounds__(256) void k_gemm40(const u16* __restrict__ A,
                                                const float* __restrict__ W,
                                                float* __restrict__ C,
                                                const float* __restrict__ dinv,
                                                int M) {
    __shared__ float Ws[128 * 40];
    for (int i = threadIdx.x; i < 128 * 40; i += 256) Ws[i] = W[i];
    __syncthreads();
    int r0 = blockIdx.x * 512 + threadIdx.x;
    int r1 = r0 + 256;
    float acc0[40], acc1[40];
#pragma unroll
    for (int c = 0; c < 40; ++c) { acc0[c] = 0.f; acc1[c] = 0.f; }
    const uint2* x0 = (const uint2*)(A + (size_t)min(r0, M - 1) * 128);
    const uint2* x1 = (const uint2*)(A + (size_t)min(r1, M - 1) * 128);
    for (int kb = 0; kb < 32; ++kb) {
        uint2 ua = x0[kb];
        uint2 ub = x1[kb];
        float a0x = bflo(ua.x), a0y = bfhi(ua.x), a0z = bflo(ua.y), a0w = bfhi(ua.y);
        float a1x = bflo(ub.x), a1y = bfhi(ub.x), a1z = bflo(ub.y), a1w = bfhi(ub.y);
        const float* wr = &Ws[kb * 160];
#pragma unroll
        for (int c4 = 0; c4 < 10; ++c4) {
            float4 wk0 = *(const float4*)&wr[c4 * 4];
            float4 wk1 = *(const float4*)&wr[40 + c4 * 4];
            float4 wk2 = *(const float4*)&wr[80 + c4 * 4];
            float4 wk3 = *(const float4*)&wr[120 + c4 * 4];
            int c = c4 * 4;
            acc0[c+0] = fmaf(a0x,wk0.x, fmaf(a0y,wk1.x, fmaf(a0z,wk2.x, fmaf(a0w,wk3.x, acc0[c+0]))));
            acc0[c+1] = fmaf(a0x,wk0.y, fmaf(a0y,wk1.y, fmaf(a0z,wk2.y, fmaf(a0w,wk3.y, acc0[c+1]))));
            acc0[c+2] = fmaf(a0x,wk0.z, fmaf(a0y,wk1.z, fmaf(a0z,wk2.z, fmaf(a0w,wk3.z, acc0[c+2]))));
            acc0[c+3] = fmaf(a0x,wk0.w, fmaf(a0y,wk1.w, fmaf(a0z,wk2.w, fmaf(a0w,wk3.w, acc0[c+3]))));
            acc1[c+0] = fmaf(a1x,wk0.x, fmaf(a1y,wk1.x, fmaf(a1z,wk2.x, fmaf(a1w,wk3.x, acc1[c+0]))));
            acc1[c+1] = fmaf(a1x,wk0.y, fmaf(a1y,wk1.y, fmaf(a1z,wk2.y, fmaf(a1w,wk3.y, acc1[c+1]))));
            acc1[c+2] = fmaf(a1x,wk0.z, fmaf(a1y,wk1.z, fmaf(a1z,wk2.z, fmaf(a1w,wk3.z, acc1[c+2]))));
            acc1[c+3] = fmaf(a1x,wk0.w, fmaf(a1y,wk1.w, fmaf(a1z,wk2.w, fmaf(a1w,wk3.w, acc1[c+3]))));
        }
    }
    if (r0 < M) {
        float s = dinv[r0];
#pragma unroll
        for (int c4 = 0; c4 < 10; ++c4)
            *(float4*)&C[(size_t)r0 * 40 + c4 * 4] =
                make_float4(s*acc0[c4*4], s*acc0[c4*4+1], s*acc0[c4*4+2], s*acc0[c4*4+3]);
    }
    if (r1 < M) {
        float s = dinv[r1];
#pragma unroll
        for (int c4 = 0; c4 < 10; ++c4)
            *(float4*)&C[(size_t)r1 * 40 + c4 * 4] =
                make_float4(s*acc1[c4*4], s*acc1[c4*4+1], s*acc1[c4*4+2], s*acc1[c4*4+3]);
    }
}

// ------------------------------ aggregation --------------------------------

// d=128 bf16 gather-sum; 2 nodes per wave (32 lanes x 4 feats each);
// 8/2/1 unrolled edge loop; fused bias+BN+ReLU; bf16 in/out.
__global__ __launch_bounds__(256) void k_agg128(const u16* __restrict__ X,
                                                u16* __restrict__ Y,
                                                const int* __restrict__ row,
                                                const int* __restrict__ col,
                                                const float* __restrict__ dinv,
                                                const float* __restrict__ bias,
                                                const float* __restrict__ g,
                                                const float* __restrict__ be,
                                                const float* __restrict__ mean,
                                                const float* __restrict__ var,
                                                int n) {
    int tid = threadIdx.x;
    int wid = tid >> 6, lane = tid & 63;
    int half = lane >> 5, l5 = lane & 31;
    int node = (blockIdx.x * 4 + wid) * 2 + half;
    bool valid = node < n;
    int nc = valid ? node : (n - 1);
    const uint2* xp = (const uint2*)X;  // 32 x uint2 per row (4 bf16 each)
    int s = row[nc], e = row[nc + 1];
    uint2 v = xp[(size_t)nc * 32 + l5];  // self (pre-scaled)
    float a0 = bflo(v.x), a1 = bfhi(v.x), a2 = bflo(v.y), a3 = bfhi(v.y);
    float b0 = 0, b1 = 0, b2 = 0, b3 = 0;
    float c0 = 0, c1 = 0, c2 = 0, c3 = 0;
    float d0 = 0, d1 = 0, d2 = 0, d3 = 0;
    int j = s;
    for (; j + 8 <= e; j += 8) {
        int e0 = col[j], e1 = col[j+1], e2 = col[j+2], e3 = col[j+3];
        int e4 = col[j+4], e5 = col[j+5], e6 = col[j+6], e7 = col[j+7];
        uint2 x0 = xp[(size_t)e0 * 32 + l5];
        uint2 x1 = xp[(size_t)e1 * 32 + l5];
        uint2 x2 = xp[(size_t)e2 * 32 + l5];
        uint2 x3 = xp[(size_t)e3 * 32 + l5];
        uint2 x4 = xp[(size_t)e4 * 32 + l5];
        uint2 x5 = xp[(size_t)e5 * 32 + l5];
        uint2 x6 = xp[(size_t)e6 * 32 + l5];
        uint2 x7 = xp[(size_t)e7 * 32 + l5];
        a0 += bflo(x0.x); a1 += bfhi(x0.x); a2 += bflo(x0.y); a3 += bfhi(x0.y);
        b0 += bflo(x1.x); b1 += bfhi(x1.x); b2 += bflo(x1.y); b3 += bfhi(x1.y);
        c0 += bflo(x2.x); c1 += bfhi(x2.x); c2 += bflo(x2.y); c3 += bfhi(x2.y);
        d0 += bflo(x3.x); d1 += bfhi(x3.x); d2 += bflo(x3.y); d3 += bfhi(x3.y);
        a0 += bflo(x4.x); a1 += bfhi(x4.x); a2 += bflo(x4.y); a3 += bfhi(x4.y);
        b0 += bflo(x5.x); b1 += bfhi(x5.x); b2 += bflo(x5.y); b3 += bfhi(x5.y);
        c0 += bflo(x6.x); c1 += bfhi(x6.x); c2 += bflo(x6.y); c3 += bfhi(x6.y);
        d0 += bflo(x7.x); d1 += bfhi(x7.x); d2 += bflo(x7.y); d3 += bfhi(x7.y);
    }
    for (; j + 2 <= e; j += 2) {
        int e0 = col[j], e1 = col[j+1];
        uint2 x0 = xp[(size_t)e0 * 32 + l5];
        uint2 x1 = xp[(size_t)e1 * 32 + l5];
        a0 += bflo(x0.x); a1 += bfhi(x0.x); a2 += bflo(x0.y); a3 += bfhi(x0.y);
        b0 += bflo(x1.x); b1 += bfhi(x1.x); b2 += bflo(x1.y); b3 += bfhi(x1.y);
    }
    if (j < e) {
        uint2 x0 = xp[(size_t)col[j] * 32 + l5];
        c0 += bflo(x0.x); c1 += bfhi(x0.x); c2 += bflo(x0.y); c3 += bfhi(x0.y);
    }
    float dv = dinv[nc];
    float s0 = dv * ((a0 + b0) + (c0 + d0));
    float s1 = dv * ((a1 + b1) + (c1 + d1));
    float s2 = dv * ((a2 + b2) + (c2 + d2));
    float s3 = dv * ((a3 + b3) + (c3 + d3));
    float4 g4 = ((const float4*)g)[l5];
    float4 be4 = ((const float4*)be)[l5];
    float4 m4 = ((const float4*)mean)[l5];
    float4 v4 = ((const float4*)var)[l5];
    float4 bi4 = ((const float4*)bias)[l5];
    float sc0 = g4.x * rsqrtf(v4.x + 1e-5f);
    float sc1 = g4.y * rsqrtf(v4.y + 1e-5f);
    float sc2 = g4.z * rsqrtf(v4.z + 1e-5f);
    float sc3 = g4.w * rsqrtf(v4.w + 1e-5f);
    float y0 = fmaxf(fmaf(sc0, s0, fmaf(sc0, bi4.x - m4.x, be4.x)), 0.f);
    float y1 = fmaxf(fmaf(sc1, s1, fmaf(sc1, bi4.y - m4.y, be4.y)), 0.f);
    float y2 = fmaxf(fmaf(sc2, s2, fmaf(sc2, bi4.z - m4.z, be4.z)), 0.f);
    float y3 = fmaxf(fmaf(sc3, s3, fmaf(sc3, bi4.w - m4.w, be4.w)), 0.f);
    if (valid) {
        uint2 o;
        o.x = pack2(y0, y1);
        o.y = pack2(y2, y3);
        ((uint2*)Y)[(size_t)node * 32 + l5] = o;
    }
}

// d=40 fp32 gather-sum + bias + log_softmax (lanes 0..39 active).
__global__ __launch_bounds__(256) void k_agg40(const float* __restrict__ X,
                                               float* __restrict__ out,
                                               const int* __restrict__ row,
                                               const int* __restrict__ col,
                                               const float* __restrict__ dinv,
                                               const float* __restrict__ b2,
                                               int n) {
    int wid = threadIdx.x >> 6;
    int lane = threadIdx.x & 63;
    int node = blockIdx.x * 4 + wid;
    if (node >= n) return;
    bool active = lane < 40;
    int s = row[node], e = row[node + 1];
    float a0 = 0.f, a1 = 0.f, a2 = 0.f, a3 = 0.f;
    float a4 = 0.f, a5 = 0.f, a6 = 0.f, a7 = 0.f;
    if (active) a0 = X[(size_t)node * 40 + lane];  // self (pre-scaled)
    int j = s;
    for (; j + 8 <= e; j += 8) {
        int c0 = col[j], c1 = col[j+1], c2 = col[j+2], c3 = col[j+3];
        int c4 = col[j+4], c5 = col[j+5], c6 = col[j+6], c7 = col[j+7];
        if (active) {
            a0 += X[(size_t)c0 * 40 + lane];
            a1 += X[(size_t)c1 * 40 + lane];
            a2 += X[(size_t)c2 * 40 + lane];
            a3 += X[(size_t)c3 * 40 + lane];
            a4 += X[(size_t)c4 * 40 + lane];
            a5 += X[(size_t)c5 * 40 + lane];
            a6 += X[(size_t)c6 * 40 + lane];
            a7 += X[(size_t)c7 * 40 + lane];
        }
    }
    for (; j + 2 <= e; j += 2) {
        int c0 = col[j], c1 = col[j+1];
        if (active) {
            a0 += X[(size_t)c0 * 40 + lane];
            a1 += X[(size_t)c1 * 40 + lane];
        }
    }
    if (j < e && active) a2 += X[(size_t)col[j] * 40 + lane];
    float v = dinv[node];
    float tot = ((a0 + a1) + (a2 + a3)) + ((a4 + a5) + (a6 + a7));
    float y = active ? fmaf(v, tot, b2[lane]) : -INFINITY;
    float m = y;
#pragma unroll
    for (int d = 32; d; d >>= 1) m = fmaxf(m, __shfl_xor(m, d));
    float ex = active ? __expf(y - m) : 0.f;
    float ssum = ex;
#pragma unroll
    for (int d = 32; d; d >>= 1) ssum += __shfl_xor(ssum, d);
    if (active) out[(size_t)node * 40 + lane] = y - m - __logf(ssum);
}

// --------------------------------- launch ----------------------------------

extern "C" void kernel_launch(void* const* d_in, const int* in_sizes, int n_in,
                              void* d_out, int out_size, void* d_ws, size_t ws_size,
                              hipStream_t stream) {
    const float* x   = (const float*)d_in[0];
    const int*   ei  = (const int*)d_in[1];
    const float* W0  = (const float*)d_in[2];
    const float* b0  = (const float*)d_in[3];
    const float* W1  = (const float*)d_in[4];
    const float* b1  = (const float*)d_in[5];
    const float* W2  = (const float*)d_in[6];
    const float* b2  = (const float*)d_in[7];
    const float* g0  = (const float*)d_in[8];
    const float* be0 = (const float*)d_in[9];
    const float* m0  = (const float*)d_in[10];
    const float* v0  = (const float*)d_in[11];
    const float* g1  = (const float*)d_in[12];
    const float* be1 = (const float*)d_in[13];
    const float* m1  = (const float*)d_in[14];
    const float* v1  = (const float*)d_in[15];
    float* out = (float*)d_out;

    int N = in_sizes[0] / 128;
    int E = in_sizes[1] / 2;
    const int* src = ei;
    const int* dst = ei + E;

    int NB = (N + CSZ - 1) / CSZ;  // coarse buckets (<=256)

    char* ws = (char*)d_ws;
    size_t off = 0;
    auto alloc = [&](size_t bytes) -> char* {
        char* p = ws + off;
        off += (bytes + 255) & ~(size_t)255;
        return p;
    };
    u16*   XsA   = (u16*)alloc((size_t)N * 128 * 2);   // gemm out / agg in
    u16*   hB    = (u16*)alloc((size_t)N * 128 * 2);   // agg out / gemm in
    float* bufC  = (float*)alloc((size_t)N * 40 * 4);
    int*   col   = (int*)alloc((size_t)E * 4);
    int*   row   = (int*)alloc((size_t)(N + 1) * 4);
    float* dinv  = (float*)alloc((size_t)N * 4);
    int*   hist1 = (int*)alloc((size_t)(NB + 1) * 4);
    int*   base1 = (int*)alloc((size_t)(NB + 1) * 4);
    int*   cur1  = (int*)alloc((size_t)(NB + 1) * 4);
    u32*   bkt   = (u32*)XsA;  // alias: bkt dead before gemm0 writes XsA

    hipMemsetAsync(hist1, 0, (size_t)(NB + 1) * 4, stream);
    k_hist1<<<(E + 4095) / 4096, 256, 0, stream>>>(dst, hist1, E, NB);
    k_scan1<<<1, 256, 0, stream>>>(hist1, base1, cur1, NB, E);
    k_part1<<<(E + PCHUNK - 1) / PCHUNK, 256, 0, stream>>>(src, dst, cur1, bkt, E, NB);
    k_csr<<<NB, 256, 0, stream>>>(bkt, base1, col, row, dinv, N, E);

    k_gemm128<false><<<(N + 127) / 128, 256, 0, stream>>>(x, W0, XsA, dinv, N);
    k_agg128<<<(N + 7) / 8, 256, 0, stream>>>(XsA, hB, row, col, dinv, b0, g0, be0, m0, v0, N);
    k_gemm128<true><<<(N + 127) / 128, 256, 0, stream>>>(hB, W1, XsA, dinv, N);
    k_agg128<<<(N + 7) / 8, 256, 0, stream>>>(XsA, hB, row, col, dinv, b1, g1, be1, m1, v1, N);
    k_gemm40<<<(N + 511) / 512, 256, 0, stream>>>(hB, W2, bufC, dinv, N);
    k_agg40<<<(N + 3) / 4, 256, 0, stream>>>(bufC, out, row, col, dinv, b2, N);
}

// Round 6
// 315.709 us; speedup vs baseline: 2.7022x; 1.2592x over previous
//
#include <hip/hip_runtime.h>
#include <math.h>

// ---------------------------------------------------------------------------
// GCN 3-layer inference. bf16 data path, fp32 accumulation.
// CSR build via LDS-multisplit radix partition (dense global writes).
// gemm128 = MFMA bf16 (LDS-free: per-wave 16x128 tile, frag-packed W).
// agg identity: out[n] = dinv[n]*( Xs[n] + sum_e Xs[col] ),  Xs = dinv.*(A@W)
// ---------------------------------------------------------------------------

#define CSHIFT 9
#define CSZ 512         // nodes per coarse bucket
#define PCHUNK 8192     // edges per k_part1 block

typedef unsigned short u16;
typedef unsigned int u32;
typedef unsigned char u8;
typedef float f32x4 __attribute__((ext_vector_type(4)));
typedef short s16x8 __attribute__((ext_vector_type(8)));

__device__ inline float bflo(u32 u) { return __uint_as_float(u << 16); }
__device__ inline float bfhi(u32 u) { return __uint_as_float(u & 0xffff0000u); }
__device__ inline u16 f2bf(float f) {  // RNE
    u32 b = __float_as_uint(f);
    b += 0x7fff + ((b >> 16) & 1);
    return (u16)(b >> 16);
}
__device__ inline u32 pack2(float lo, float hi) {
    return (u32)f2bf(lo) | ((u32)f2bf(hi) << 16);
}

// ------------------------------- CSR build ---------------------------------

__global__ __launch_bounds__(256) void k_hist1(const int* __restrict__ dst,
                                               int* __restrict__ hist1,
                                               int E, int NB) {
    __shared__ int h[256];
    int t = threadIdx.x;
    h[t] = 0;
    __syncthreads();
    for (int i = blockIdx.x * 256 * 16 + t; i < min(E, (blockIdx.x + 1) * 256 * 16);
         i += 256)
        atomicAdd(&h[dst[i] >> CSHIFT], 1);
    __syncthreads();
    if (t < NB && h[t]) atomicAdd(&hist1[t], h[t]);
}

__global__ __launch_bounds__(256) void k_scan1(const int* __restrict__ hist1,
                                               int* __restrict__ base1,
                                               int* __restrict__ cur1,
                                               int NB, int E) {
    __shared__ int sc[256];
    int t = threadIdx.x;
    int v = (t < NB) ? hist1[t] : 0;
    sc[t] = v;
    __syncthreads();
    for (int d = 1; d < 256; d <<= 1) {
        int add = (t >= d) ? sc[t - d] : 0;
        __syncthreads();
        sc[t] += add;
        __syncthreads();
    }
    if (t < NB) {
        int excl = sc[t] - v;
        base1[t] = excl;
        cur1[t] = excl;
    }
    if (t == 0) base1[NB] = E;
}

__global__ __launch_bounds__(256) void k_part1(const int* __restrict__ src,
                                               const int* __restrict__ dst,
                                               int* __restrict__ cur1,
                                               u32* __restrict__ bkt,
                                               int E, int NB) {
    __shared__ u32 stage[PCHUNK];
    __shared__ u8 sbin[PCHUNK];
    __shared__ int cnt[256];
    __shared__ int lbase[256];
    __shared__ int lcur[256];
    __shared__ int gb[256];
    int t = threadIdx.x;
    int base = blockIdx.x * PCHUNK;
    int n = min(PCHUNK, E - base);
    cnt[t] = 0;
    __syncthreads();
    for (int i = t; i < n; i += 256) atomicAdd(&cnt[dst[base + i] >> CSHIFT], 1);
    __syncthreads();
    int v = cnt[t];
    lbase[t] = v;
    __syncthreads();
    for (int d = 1; d < 256; d <<= 1) {
        int add = (t >= d) ? lbase[t - d] : 0;
        __syncthreads();
        lbase[t] += add;
        __syncthreads();
    }
    {
        int excl = lbase[t] - v;
        __syncthreads();
        lbase[t] = excl;
        lcur[t] = excl;
        if (t < NB && v) gb[t] = atomicAdd(&cur1[t], v);
    }
    __syncthreads();
    for (int i = t; i < n; i += 256) {
        int d = dst[base + i];
        int s = src[base + i];
        int bin = d >> CSHIFT;
        int p = atomicAdd(&lcur[bin], 1);
        stage[p] = ((u32)s << CSHIFT) | (u32)(d & (CSZ - 1));
        sbin[p] = (u8)bin;
    }
    __syncthreads();
    for (int k = t; k < n; k += 256) {
        int bin = sbin[k];
        bkt[gb[bin] + (k - lbase[bin])] = stage[k];
    }
}

__global__ __launch_bounds__(256) void k_csr(const u32* __restrict__ bkt,
                                             const int* __restrict__ base1,
                                             int* __restrict__ col,
                                             int* __restrict__ row,
                                             float* __restrict__ dinv,
                                             int N, int E) {
    __shared__ int deg[CSZ];
    __shared__ int cur[CSZ];
    __shared__ int sc[256];
    int b = blockIdx.x;
    int t = threadIdx.x;
    int start = base1[b];
    int end = base1[b + 1];
    int nbase = b << CSHIFT;
    deg[t] = 0;
    deg[t + 256] = 0;
    __syncthreads();
    for (int i = start + t; i < end; i += 256)
        atomicAdd(&deg[bkt[i] & (CSZ - 1)], 1);
    __syncthreads();
    int d0 = deg[2 * t], d1 = deg[2 * t + 1];
    int s = d0 + d1;
    sc[t] = s;
    __syncthreads();
    for (int d = 1; d < 256; d <<= 1) {
        int add = (t >= d) ? sc[t - d] : 0;
        __syncthreads();
        sc[t] += add;
        __syncthreads();
    }
    int excl = sc[t] - s;
    cur[2 * t] = excl;
    cur[2 * t + 1] = excl + d0;
    int n0 = nbase + 2 * t, n1 = n0 + 1;
    if (n0 < N) { row[n0] = start + excl;      dinv[n0] = rsqrtf((float)(d0 + 1)); }
    if (n1 < N) { row[n1] = start + excl + d0; dinv[n1] = rsqrtf((float)(d1 + 1)); }
    __syncthreads();
    for (int i = start + t; i < end; i += 256) {
        u32 v = bkt[i];
        int p = start + atomicAdd(&cur[v & (CSZ - 1)], 1);
        col[p] = (int)(v >> CSHIFT);
    }
    if (b == 0 && t == 0) row[N] = E;
}

// --------------------------------- GEMMs -----------------------------------

// Pack W[128x128] fp32 into bf16 MFMA B-fragment order:
// Wpk16[(((ks*8+ct)*64)+l)*8+j] = bf16( W[(ks*32 + 8*(l>>4)+j)*128 + ct*16 + (l&15)] )
__global__ __launch_bounds__(256) void k_packW(const float* __restrict__ W,
                                               u16* __restrict__ Wpk) {
    int g = blockIdx.x * 256 + threadIdx.x;  // 0..16383
    int j = g & 7;
    int l = (g >> 3) & 63;
    int f = g >> 9;         // 0..31
    int ct = f & 7, ks = f >> 3;
    int krow = ks * 32 + ((l >> 4) << 3) + j;
    int wcol = ct * 16 + (l & 15);
    Wpk[g] = f2bf(W[krow * 128 + wcol]);
}

// C[r](bf16) = dinv[r] * (A[r] @ W).  MFMA 16x16x32 bf16, LDS-free.
// Wave owns 16 rows x 128 cols. A: fp32 (AFP32) or bf16.
template <bool AFP32>
__global__ __launch_bounds__(256) void k_gemm128m(const void* __restrict__ Av,
                                                  const u16* __restrict__ Wpk,
                                                  u16* __restrict__ C,
                                                  const float* __restrict__ dinv,
                                                  int M) {
    int tid = threadIdx.x;
    int wv = blockIdx.x * 4 + (tid >> 6);
    int rowbase = wv * 16;
    if (rowbase >= M) return;
    int l = tid & 63;
    int r = l & 15, hi = l >> 4;

    f32x4 acc[8];
#pragma unroll
    for (int ct = 0; ct < 8; ++ct) acc[ct] = (f32x4)(0.f);

    const uint4* wp = (const uint4*)Wpk;
#pragma unroll
    for (int ks = 0; ks < 4; ++ks) {
        s16x8 afrag;
        int abase = (rowbase + r) * 128 + ks * 32 + hi * 8;
        if (AFP32) {
            const float* A = (const float*)Av;
            float4 a0 = *(const float4*)&A[abase];
            float4 a1 = *(const float4*)&A[abase + 4];
            u32 p0 = pack2(a0.x, a0.y), p1 = pack2(a0.z, a0.w);
            u32 p2 = pack2(a1.x, a1.y), p3 = pack2(a1.z, a1.w);
            uint4 u = make_uint4(p0, p1, p2, p3);
            afrag = *(s16x8*)&u;
        } else {
            const u16* A = (const u16*)Av;
            uint4 u = *(const uint4*)&A[abase];
            afrag = *(s16x8*)&u;
        }
#pragma unroll
        for (int ct = 0; ct < 8; ++ct) {
            uint4 b = wp[(ks * 8 + ct) * 64 + l];
            s16x8 bfrag = *(s16x8*)&b;
            acc[ct] = __builtin_amdgcn_mfma_f32_16x16x32_bf16(afrag, bfrag, acc[ct], 0, 0, 0);
        }
    }
    // D: row = rowbase + 4*hi + reg, col = ct*16 + r
    float dv[4];
#pragma unroll
    for (int reg = 0; reg < 4; ++reg) dv[reg] = dinv[rowbase + 4 * hi + reg];
#pragma unroll
    for (int ct = 0; ct < 8; ++ct) {
#pragma unroll
        for (int reg = 0; reg < 4; ++reg) {
            int orow = rowbase + 4 * hi + reg;
            C[(size_t)orow * 128 + ct * 16 + r] = f2bf(dv[reg] * acc[ct][reg]);
        }
    }
}

// C[r](bf16) = dinv[r] * (A[r] @ W), A: Mx128 bf16, W: 128x40 fp32.
__global__ __launch_bounds__(256) void k_gemm40(const u16* __restrict__ A,
                                                const float* __restrict__ W,
                                                u16* __restrict__ C,
                                                const float* __restrict__ dinv,
                                                int M) {
    __shared__ float Ws[128 * 40];
    for (int i = threadIdx.x; i < 128 * 40; i += 256) Ws[i] = W[i];
    __syncthreads();
    int r0 = blockIdx.x * 512 + threadIdx.x;
    int r1 = r0 + 256;
    float acc0[40], acc1[40];
#pragma unroll
    for (int c = 0; c < 40; ++c) { acc0[c] = 0.f; acc1[c] = 0.f; }
    const uint2* x0 = (const uint2*)(A + (size_t)min(r0, M - 1) * 128);
    const uint2* x1 = (const uint2*)(A + (size_t)min(r1, M - 1) * 128);
    for (int kb = 0; kb < 32; ++kb) {
        uint2 ua = x0[kb];
        uint2 ub = x1[kb];
        float a0x = bflo(ua.x), a0y = bfhi(ua.x), a0z = bflo(ua.y), a0w = bfhi(ua.y);
        float a1x = bflo(ub.x), a1y = bfhi(ub.x), a1z = bflo(ub.y), a1w = bfhi(ub.y);
        const float* wr = &Ws[kb * 160];
#pragma unroll
        for (int c4 = 0; c4 < 10; ++c4) {
            float4 wk0 = *(const float4*)&wr[c4 * 4];
            float4 wk1 = *(const float4*)&wr[40 + c4 * 4];
            float4 wk2 = *(const float4*)&wr[80 + c4 * 4];
            float4 wk3 = *(const float4*)&wr[120 + c4 * 4];
            int c = c4 * 4;
            acc0[c+0] = fmaf(a0x,wk0.x, fmaf(a0y,wk1.x, fmaf(a0z,wk2.x, fmaf(a0w,wk3.x, acc0[c+0]))));
            acc0[c+1] = fmaf(a0x,wk0.y, fmaf(a0y,wk1.y, fmaf(a0z,wk2.y, fmaf(a0w,wk3.y, acc0[c+1]))));
            acc0[c+2] = fmaf(a0x,wk0.z, fmaf(a0y,wk1.z, fmaf(a0z,wk2.z, fmaf(a0w,wk3.z, acc0[c+2]))));
            acc0[c+3] = fmaf(a0x,wk0.w, fmaf(a0y,wk1.w, fmaf(a0z,wk2.w, fmaf(a0w,wk3.w, acc0[c+3]))));
            acc1[c+0] = fmaf(a1x,wk0.x, fmaf(a1y,wk1.x, fmaf(a1z,wk2.x, fmaf(a1w,wk3.x, acc1[c+0]))));
            acc1[c+1] = fmaf(a1x,wk0.y, fmaf(a1y,wk1.y, fmaf(a1z,wk2.y, fmaf(a1w,wk3.y, acc1[c+1]))));
            acc1[c+2] = fmaf(a1x,wk0.z, fmaf(a1y,wk1.z, fmaf(a1z,wk2.z, fmaf(a1w,wk3.z, acc1[c+2]))));
            acc1[c+3] = fmaf(a1x,wk0.w, fmaf(a1y,wk1.w, fmaf(a1z,wk2.w, fmaf(a1w,wk3.w, acc1[c+3]))));
        }
    }
    if (r0 < M) {
        float s = dinv[r0];
        u32* crow = (u32*)(C + (size_t)r0 * 40);
#pragma unroll
        for (int c2 = 0; c2 < 20; ++c2) crow[c2] = pack2(s * acc0[2*c2], s * acc0[2*c2+1]);
    }
    if (r1 < M) {
        float s = dinv[r1];
        u32* crow = (u32*)(C + (size_t)r1 * 40);
#pragma unroll
        for (int c2 = 0; c2 < 20; ++c2) crow[c2] = pack2(s * acc1[2*c2], s * acc1[2*c2+1]);
    }
}

// ------------------------------ aggregation --------------------------------

// d=128 bf16 gather-sum; 2 nodes per wave; fused bias+BN+ReLU; bf16 in/out.
__global__ __launch_bounds__(256) void k_agg128(const u16* __restrict__ X,
                                                u16* __restrict__ Y,
                                                const int* __restrict__ row,
                                                const int* __restrict__ col,
                                                const float* __restrict__ dinv,
                                                const float* __restrict__ bias,
                                                const float* __restrict__ g,
                                                const float* __restrict__ be,
                                                const float* __restrict__ mean,
                                                const float* __restrict__ var,
                                                int n) {
    int tid = threadIdx.x;
    int wid = tid >> 6, lane = tid & 63;
    int half = lane >> 5, l5 = lane & 31;
    int node = (blockIdx.x * 4 + wid) * 2 + half;
    bool valid = node < n;
    int nc = valid ? node : (n - 1);
    const uint2* xp = (const uint2*)X;
    int s = row[nc], e = row[nc + 1];
    uint2 v = xp[(size_t)nc * 32 + l5];
    float a0 = bflo(v.x), a1 = bfhi(v.x), a2 = bflo(v.y), a3 = bfhi(v.y);
    float b0 = 0, b1 = 0, b2 = 0, b3 = 0;
    float c0 = 0, c1 = 0, c2 = 0, c3 = 0;
    float d0 = 0, d1 = 0, d2 = 0, d3 = 0;
    int j = s;
    for (; j + 8 <= e; j += 8) {
        int e0 = col[j], e1 = col[j+1], e2 = col[j+2], e3 = col[j+3];
        int e4 = col[j+4], e5 = col[j+5], e6 = col[j+6], e7 = col[j+7];
        uint2 x0 = xp[(size_t)e0 * 32 + l5];
        uint2 x1 = xp[(size_t)e1 * 32 + l5];
        uint2 x2 = xp[(size_t)e2 * 32 + l5];
        uint2 x3 = xp[(size_t)e3 * 32 + l5];
        uint2 x4 = xp[(size_t)e4 * 32 + l5];
        uint2 x5 = xp[(size_t)e5 * 32 + l5];
        uint2 x6 = xp[(size_t)e6 * 32 + l5];
        uint2 x7 = xp[(size_t)e7 * 32 + l5];
        a0 += bflo(x0.x); a1 += bfhi(x0.x); a2 += bflo(x0.y); a3 += bfhi(x0.y);
        b0 += bflo(x1.x); b1 += bfhi(x1.x); b2 += bflo(x1.y); b3 += bfhi(x1.y);
        c0 += bflo(x2.x); c1 += bfhi(x2.x); c2 += bflo(x2.y); c3 += bfhi(x2.y);
        d0 += bflo(x3.x); d1 += bfhi(x3.x); d2 += bflo(x3.y); d3 += bfhi(x3.y);
        a0 += bflo(x4.x); a1 += bfhi(x4.x); a2 += bflo(x4.y); a3 += bfhi(x4.y);
        b0 += bflo(x5.x); b1 += bfhi(x5.x); b2 += bflo(x5.y); b3 += bfhi(x5.y);
        c0 += bflo(x6.x); c1 += bfhi(x6.x); c2 += bflo(x6.y); c3 += bfhi(x6.y);
        d0 += bflo(x7.x); d1 += bfhi(x7.x); d2 += bflo(x7.y); d3 += bfhi(x7.y);
    }
    for (; j + 2 <= e; j += 2) {
        int e0 = col[j], e1 = col[j+1];
        uint2 x0 = xp[(size_t)e0 * 32 + l5];
        uint2 x1 = xp[(size_t)e1 * 32 + l5];
        a0 += bflo(x0.x); a1 += bfhi(x0.x); a2 += bflo(x0.y); a3 += bfhi(x0.y);
        b0 += bflo(x1.x); b1 += bfhi(x1.x); b2 += bflo(x1.y); b3 += bfhi(x1.y);
    }
    if (j < e) {
        uint2 x0 = xp[(size_t)col[j] * 32 + l5];
        c0 += bflo(x0.x); c1 += bfhi(x0.x); c2 += bflo(x0.y); c3 += bfhi(x0.y);
    }
    float dv = dinv[nc];
    float s0 = dv * ((a0 + b0) + (c0 + d0));
    float s1 = dv * ((a1 + b1) + (c1 + d1));
    float s2 = dv * ((a2 + b2) + (c2 + d2));
    float s3 = dv * ((a3 + b3) + (c3 + d3));
    float4 g4 = ((const float4*)g)[l5];
    float4 be4 = ((const float4*)be)[l5];
    float4 m4 = ((const float4*)mean)[l5];
    float4 v4 = ((const float4*)var)[l5];
    float4 bi4 = ((const float4*)bias)[l5];
    float sc0 = g4.x * rsqrtf(v4.x + 1e-5f);
    float sc1 = g4.y * rsqrtf(v4.y + 1e-5f);
    float sc2 = g4.z * rsqrtf(v4.z + 1e-5f);
    float sc3 = g4.w * rsqrtf(v4.w + 1e-5f);
    float y0 = fmaxf(fmaf(sc0, s0, fmaf(sc0, bi4.x - m4.x, be4.x)), 0.f);
    float y1 = fmaxf(fmaf(sc1, s1, fmaf(sc1, bi4.y - m4.y, be4.y)), 0.f);
    float y2 = fmaxf(fmaf(sc2, s2, fmaf(sc2, bi4.z - m4.z, be4.z)), 0.f);
    float y3 = fmaxf(fmaf(sc3, s3, fmaf(sc3, bi4.w - m4.w, be4.w)), 0.f);
    if (valid) {
        uint2 o;
        o.x = pack2(y0, y1);
        o.y = pack2(y2, y3);
        ((uint2*)Y)[(size_t)node * 32 + l5] = o;
    }
}

// d=40 bf16 gather-sum + bias + log_softmax; 2 nodes/wave, 20 lanes x 2 feats.
__global__ __launch_bounds__(256) void k_agg40(const u16* __restrict__ X,
                                               float* __restrict__ out,
                                               const int* __restrict__ row,
                                               const int* __restrict__ col,
                                               const float* __restrict__ dinv,
                                               const float* __restrict__ b2,
                                               int n) {
    int tid = threadIdx.x;
    int wid = tid >> 6, lane = tid & 63;
    int half = lane >> 5, l5 = lane & 31;
    int node = (blockIdx.x * 4 + wid) * 2 + half;
    bool valid = node < n;
    int nc = valid ? node : (n - 1);
    bool active = l5 < 20;
    const u32* xp = (const u32*)X;  // 20 u32 per row
    int s = row[nc], e = row[nc + 1];
    float a0 = 0, a1 = 0, b0 = 0, b1 = 0, c0 = 0, c1 = 0, d0 = 0, d1 = 0;
    if (active) {
        u32 v = xp[(size_t)nc * 20 + l5];
        a0 = bflo(v); a1 = bfhi(v);
    }
    int j = s;
    for (; j + 8 <= e; j += 8) {
        int e0 = col[j], e1 = col[j+1], e2 = col[j+2], e3 = col[j+3];
        int e4 = col[j+4], e5 = col[j+5], e6 = col[j+6], e7 = col[j+7];
        if (active) {
            u32 x0 = xp[(size_t)e0 * 20 + l5];
            u32 x1 = xp[(size_t)e1 * 20 + l5];
            u32 x2 = xp[(size_t)e2 * 20 + l5];
            u32 x3 = xp[(size_t)e3 * 20 + l5];
            u32 x4 = xp[(size_t)e4 * 20 + l5];
            u32 x5 = xp[(size_t)e5 * 20 + l5];
            u32 x6 = xp[(size_t)e6 * 20 + l5];
            u32 x7 = xp[(size_t)e7 * 20 + l5];
            a0 += bflo(x0); a1 += bfhi(x0);
            b0 += bflo(x1); b1 += bfhi(x1);
            c0 += bflo(x2); c1 += bfhi(x2);
            d0 += bflo(x3); d1 += bfhi(x3);
            a0 += bflo(x4); a1 += bfhi(x4);
            b0 += bflo(x5); b1 += bfhi(x5);
            c0 += bflo(x6); c1 += bfhi(x6);
            d0 += bflo(x7); d1 += bfhi(x7);
        }
    }
    for (; j + 2 <= e; j += 2) {
        int e0 = col[j], e1 = col[j+1];
        if (active) {
            u32 x0 = xp[(size_t)e0 * 20 + l5];
            u32 x1 = xp[(size_t)e1 * 20 + l5];
            a0 += bflo(x0); a1 += bfhi(x0);
            b0 += bflo(x1); b1 += bfhi(x1);
        }
    }
    if (j < e && active) {
        u32 x0 = xp[(size_t)col[j] * 20 + l5];
        c0 += bflo(x0); c1 += bfhi(x0);
    }
    float dv = dinv[nc];
    float ylo = -INFINITY, yhi = -INFINITY;
    if (active) {
        float2 bb = ((const float2*)b2)[l5];
        ylo = fmaf(dv, (a0 + b0) + (c0 + d0), bb.x);
        yhi = fmaf(dv, (a1 + b1) + (c1 + d1), bb.y);
    }
    float m = fmaxf(ylo, yhi);
#pragma unroll
    for (int d = 16; d; d >>= 1) m = fmaxf(m, __shfl_xor(m, d));
    float ex = active ? (__expf(ylo - m) + __expf(yhi - m)) : 0.f;
#pragma unroll
    for (int d = 16; d; d >>= 1) ex += __shfl_xor(ex, d);
    if (valid && active) {
        float lse = m + __logf(ex);
        ((float2*)out)[(size_t)node * 20 + l5] = make_float2(ylo - lse, yhi - lse);
    }
}

// --------------------------------- launch ----------------------------------

extern "C" void kernel_launch(void* const* d_in, const int* in_sizes, int n_in,
                              void* d_out, int out_size, void* d_ws, size_t ws_size,
                              hipStream_t stream) {
    const float* x   = (const float*)d_in[0];
    const int*   ei  = (const int*)d_in[1];
    const float* W0  = (const float*)d_in[2];
    const float* b0  = (const float*)d_in[3];
    const float* W1  = (const float*)d_in[4];
    const float* b1  = (const float*)d_in[5];
    const float* W2  = (const float*)d_in[6];
    const float* b2  = (const float*)d_in[7];
    const float* g0  = (const float*)d_in[8];
    const float* be0 = (const float*)d_in[9];
    const float* m0  = (const float*)d_in[10];
    const float* v0  = (const float*)d_in[11];
    const float* g1  = (const float*)d_in[12];
    const float* be1 = (const float*)d_in[13];
    const float* m1  = (const float*)d_in[14];
    const float* v1  = (const float*)d_in[15];
    float* out = (float*)d_out;

    int N = in_sizes[0] / 128;
    int E = in_sizes[1] / 2;
    const int* src = ei;
    const int* dst = ei + E;

    int NB = (N + CSZ - 1) / CSZ;  // coarse buckets (<=256)

    char* ws = (char*)d_ws;
    size_t off = 0;
    auto alloc = [&](size_t bytes) -> char* {
        char* p = ws + off;
        off += (bytes + 255) & ~(size_t)255;
        return p;
    };
    u16*   XsA   = (u16*)alloc((size_t)N * 128 * 2);   // gemm out / agg in
    u16*   hB    = (u16*)alloc((size_t)N * 128 * 2);   // agg out / gemm in
    u16*   bufC  = (u16*)alloc((size_t)N * 40 * 2);
    int*   col   = (int*)alloc((size_t)E * 4);
    int*   row   = (int*)alloc((size_t)(N + 1) * 4);
    float* dinv  = (float*)alloc((size_t)N * 4);
    int*   hist1 = (int*)alloc((size_t)(NB + 1) * 4);
    int*   base1 = (int*)alloc((size_t)(NB + 1) * 4);
    int*   cur1  = (int*)alloc((size_t)(NB + 1) * 4);
    u16*   Wpk0  = (u16*)alloc(128 * 128 * 2);
    u16*   Wpk1  = (u16*)alloc(128 * 128 * 2);
    u32*   bkt   = (u32*)XsA;  // alias: bkt dead before gemm0 writes XsA

    hipMemsetAsync(hist1, 0, (size_t)(NB + 1) * 4, stream);
    k_hist1<<<(E + 4095) / 4096, 256, 0, stream>>>(dst, hist1, E, NB);
    k_scan1<<<1, 256, 0, stream>>>(hist1, base1, cur1, NB, E);
    k_part1<<<(E + PCHUNK - 1) / PCHUNK, 256, 0, stream>>>(src, dst, cur1, bkt, E, NB);
    k_csr<<<NB, 256, 0, stream>>>(bkt, base1, col, row, dinv, N, E);
    k_packW<<<64, 256, 0, stream>>>(W0, Wpk0);
    k_packW<<<64, 256, 0, stream>>>(W1, Wpk1);

    int gemmGrid = ((N + 15) / 16 + 3) / 4;
    k_gemm128m<true><<<gemmGrid, 256, 0, stream>>>(x, Wpk0, XsA, dinv, N);
    k_agg128<<<(N + 7) / 8, 256, 0, stream>>>(XsA, hB, row, col, dinv, b0, g0, be0, m0, v0, N);
    k_gemm128m<false><<<gemmGrid, 256, 0, stream>>>(hB, Wpk1, XsA, dinv, N);
    k_agg128<<<(N + 7) / 8, 256, 0, stream>>>(XsA, hB, row, col, dinv, b1, g1, be1, m1, v1, N);
    k_gemm40<<<(N + 511) / 512, 256, 0, stream>>>(hB, W2, bufC, dinv, N);
    k_agg40<<<(N + 7) / 8, 256, 0, stream>>>(bufC, out, row, col, dinv, b2, N);
}